// Round 13
// baseline (427.989 us; speedup 1.0000x reference)
//
#include <hip/hip_runtime.h>
#include <hip/hip_bf16.h>
#include <math.h>

// LSD (local shape descriptors), 128^3, 8 labels, sigma=5, truncate=3 -> 31-tap kernel.
//
// Algebra: for label mask m, define G_{abc} = (k_a *_z)(k_b *_y)(k_c *_x) m with
//   k0(u)=w(u), k1(u)=u w(u), k2(u)=u^2 w(u)  (w = normalized gaussian).
// At a voxel with mass=G000>0, p=G100/mass, q=G010/mass, s=G001/mass:
//   mean_offset = 0.5 - {p,q,s}/(2 sigma);  cov_ab = (G../mass - ..)/sigma^2.
// Translation-invariant: coords input not needed. Masks disjoint.
//
// Measured record (totals; pass_yx in parens):
//   R11 407 (289, bf16+kp, best pass_yx)  R16 409 (313)  R17 405 (302)
//   R19 423 (302)  R20 420 (296; x-pair pass_z refuted, rest 124)
//   Occupancy/TLP levers refuted across R12-R15/R19/R20; interleaved Bu
//   refuted (R16/R17); full unroll refuted (R18).
// R21 (this round): consolidation + depth-3 pipeline.
//   a) pass_z: revert to proven 512-blk 4-x form (R11/R17 shape, bf16 out).
//   b) both conv windows: pipeline depth 2 -> 3 (+6 VGPR), covering ~774
//      issue-cycles vs ~516 -- targets the HBM-latency tail of A/seg reads
//      (FETCH 59MB < A 100MB => some true HBM misses at ~900cy).
//   c) pass_yx otherwise R11-exact (bf16 A, kp table, LCAP 512, planar Bu).

constexpr int NV = 128 * 128 * 128;
constexpr int SLICE = 128 * 128;
constexpr int R = 15;
constexpr int KL = 31;
constexpr int CSTRIDE = 160;            // u16: 16 pad + 128 data + 16 pad
constexpr int RSTRIDE = 6 * CSTRIDE + 8; // 968 u16; row stagger: 242w = 18 mod 32
constexpr int LCAP = 512;

struct Kw { float k0[KL]; float k1[KL]; float k2[KL]; };

__device__ __forceinline__ void fma4(float4& a, float w, const float4& b) {
    a.x = fmaf(w, b.x, a.x); a.y = fmaf(w, b.y, a.y);
    a.z = fmaf(w, b.z, a.z); a.w = fmaf(w, b.w, a.w);
}

__device__ __forceinline__ float4 load_mask4(const unsigned char* p, int lab) {
    unsigned int u = *(const unsigned int*)p;
    return make_float4(((u       ) & 255u) == (unsigned)lab ? 1.f : 0.f,
                       ((u >>  8 ) & 255u) == (unsigned)lab ? 1.f : 0.f,
                       ((u >> 16 ) & 255u) == (unsigned)lab ? 1.f : 0.f,
                       ((u >> 24 ) & 255u) == (unsigned)lab ? 1.f : 0.f);
}
__device__ __forceinline__ float4 load_mask4(const int* p, int lab) {
    int4 s = *(const int4*)p;
    return make_float4(s.x == lab ? 1.f : 0.f, s.y == lab ? 1.f : 0.f,
                       s.z == lab ? 1.f : 0.f, s.w == lab ? 1.f : 0.f);
}

__device__ __forceinline__ unsigned seg_pack4(const unsigned char* p) {
    return *(const unsigned int*)p;
}
__device__ __forceinline__ unsigned seg_pack4(const int* p) {
    int4 v = *(const int4*)p;
    return (unsigned)(v.x & 255) | ((unsigned)(v.y & 255) << 8) |
           ((unsigned)(v.z & 255) << 16) | ((unsigned)(v.w & 255) << 24);
}

__device__ __forceinline__ float bf_ld(const unsigned short* p) {
    return __uint_as_float(((unsigned int)(*p)) << 16);
}

// 4 packed bf16 (as uint2) -> float4. 1 VALU op per value.
__device__ __forceinline__ float4 bf4_to_f4(uint2 u) {
    return make_float4(__uint_as_float(u.x << 16),
                       __uint_as_float(u.x & 0xFFFF0000u),
                       __uint_as_float(u.y << 16),
                       __uint_as_float(u.y & 0xFFFF0000u));
}

__device__ __forceinline__ unsigned pack_bf2(float a, float b) {
    __hip_bfloat162 h = __float22bfloat162_rn(make_float2(a, b));
    return *reinterpret_cast<unsigned*>(&h);
}

// -------- pass_z: seg -> A[lab][3] bf16 (z-conv). grid (512, nlab), 256 thr.
// Proven 4-x form; 3-deep pipelined sliding window.
template <typename ST>
__global__ __launch_bounds__(256) void pass_z_t(const ST* __restrict__ seg,
                                                unsigned short* __restrict__ A,
                                                int label0, size_t a_stride,
                                                Kw kw) {
    __shared__ float kp[3][37];           // zero-padded: kp[c][i] = k_c[i-3]
    if (threadIdx.x < 37) {
        int i = threadIdx.x, j = i - 3; bool ok = (j >= 0) && (j < KL);
        kp[0][i] = ok ? kw.k0[j] : 0.f;
        kp[1][i] = ok ? kw.k1[j] : 0.f;
        kp[2][i] = ok ? kw.k2[j] : 0.f;
    }
    __syncthreads();
    const int label = label0 + blockIdx.y;
    unsigned short* Ab = A + (size_t)blockIdx.y * a_stride;
    const int h = blockIdx.x, g = h & 7, l = h >> 3;       // 512 x-blocks
    const int tx = threadIdx.x & 31, ty = threadIdx.x >> 5;
    const int x0 = tx * 4;
    const int z0 = 16 * g + 4 * (l & 3);                   // XCD g owns z [16g,16g+16)
    const int y  = (l >> 2) * 8 + ty;

    float4 acc[4][3];
#pragma unroll
    for (int t = 0; t < 4; ++t)
#pragma unroll
        for (int c = 0; c < 3; ++c) acc[t][c] = make_float4(0.f, 0.f, 0.f, 0.f);

    // 3-deep pipelined sliding window: load j+3 while FMAing j.
    float4 p0 = make_float4(0.f, 0.f, 0.f, 0.f), p1 = p0, p2 = p0;
    {
#pragma unroll
        for (int d = 0; d < 3; ++d) {
            int zz = z0 + d - R;
            float4 m = make_float4(0.f, 0.f, 0.f, 0.f);
            if ((unsigned)zz < 128u)
                m = load_mask4(seg + (zz * SLICE + y * 128 + x0), label);
            if (d == 0) p0 = m; else if (d == 1) p1 = m; else p2 = m;
        }
    }
    for (int j = 0; j < 34; ++j) {                         // window: 4 outs + 30
        float4 fm = make_float4(0.f, 0.f, 0.f, 0.f);
        int zz = z0 + j + 3 - R;                           // uniform per wave
        if (j < 31 && (unsigned)zz < 128u)
            fm = load_mask4(seg + (zz * SLICE + y * 128 + x0), label);
#pragma unroll
        for (int t = 0; t < 4; ++t) {
            int i = j - t + 3;                             // padded weight index
            fma4(acc[t][0], kp[0][i], p0);
            fma4(acc[t][1], kp[1][i], p0);
            fma4(acc[t][2], kp[2][i], p0);
        }
        p0 = p1; p1 = p2; p2 = fm;
    }
#pragma unroll
    for (int t = 0; t < 4; ++t) {
        int base = (z0 + t) * SLICE + y * 128 + x0;
#pragma unroll
        for (int c = 0; c < 3; ++c) {
            float4 v = acc[t][c];
            uint2 pv = make_uint2(pack_bf2(v.x, v.y), pack_bf2(v.z, v.w));
            *reinterpret_cast<uint2*>(Ab + (size_t)c * NV + base) = pv;
        }
    }
}

// ---- per-voxel sparse x-conv + epilogue (B rows in bf16 LDS, zero-padded) -
__device__ __forceinline__ void conv_voxel(const unsigned short* __restrict__ Bu,
                                           int rr, int x, const Kw& kw,
                                           float o[10]) {
    const unsigned short* row = Bu + rr * RSTRIDE + (x + 1);
    float g000 = 0, g001 = 0, g002 = 0, g010 = 0, g011 = 0,
          g020 = 0, g100 = 0, g101 = 0, g110 = 0, g200 = 0;
#pragma unroll
    for (int j = 0; j < KL; ++j) {
        float w0 = kw.k0[j], w1 = kw.k1[j], w2 = kw.k2[j];
        float b0 = bf_ld(row + 0 * CSTRIDE + j);
        float b1 = bf_ld(row + 1 * CSTRIDE + j);
        float b2 = bf_ld(row + 2 * CSTRIDE + j);
        float b3 = bf_ld(row + 3 * CSTRIDE + j);
        float b4 = bf_ld(row + 4 * CSTRIDE + j);
        float b5 = bf_ld(row + 5 * CSTRIDE + j);
        g000 = fmaf(w0, b0, g000); g001 = fmaf(w1, b0, g001); g002 = fmaf(w2, b0, g002);
        g010 = fmaf(w0, b1, g010); g011 = fmaf(w1, b1, g011);
        g020 = fmaf(w0, b2, g020);
        g100 = fmaf(w0, b3, g100); g101 = fmaf(w1, b3, g101);
        g110 = fmaf(w0, b4, g110);
        g200 = fmaf(w0, b5, g200);
    }
    float mass = g000;
    float denom = (mass > 0.f) ? mass : 1.f;
    float inv = 1.f / denom;
    float p = g100 * inv, q = g010 * inv, s = g001 * inv;
    const float cs = 1.0f / 25.0f;                         // 1/sigma^2
    o[0] = 0.5f - 0.1f * p;                                // 1/(2 sigma) = 0.1
    o[1] = 0.5f - 0.1f * q;
    o[2] = 0.5f - 0.1f * s;
    o[3] = (g200 * inv - p * p) * cs;
    o[4] = (g020 * inv - q * q) * cs;
    o[5] = (g002 * inv - s * s) * cs;
    o[6] = (g110 * inv - p * q) * cs;
    o[7] = (g011 * inv - q * s) * cs;
    o[8] = (g101 * inv - p * s) * cs;
    o[9] = mass;
#pragma unroll
    for (int c = 0; c < 10; ++c) o[c] = fminf(fmaxf(o[c], 0.f), 1.f);
}

__device__ __forceinline__ void do_voxel_out(const unsigned short* __restrict__ Bu,
                                             int rr, int x, int z0, int y0,
                                             float* __restrict__ out, const Kw& kw) {
    float o[10];
    conv_voxel(Bu, rr, x, kw, o);
    const int z2 = z0 + (rr >> 2), y2 = y0 + (rr & 3);
    const int v = (z2 * 128 + y2) * 128 + x;
#pragma unroll
    for (int c = 0; c < 10; ++c) out[(size_t)c * NV + v] = o[c];
}

__device__ __forceinline__ void zero_voxel(int rr, int x, int z0, int y0,
                                           float* __restrict__ out) {
    const int z2 = z0 + (rr >> 2), y2 = y0 + (rr & 3);
    const int v = (z2 * 128 + y2) * 128 + x;
#pragma unroll
    for (int c = 0; c < 10; ++c) out[(size_t)c * NV + v] = 0.f;
}

// -------- pass_yx: A[lab][3] bf16 -> out. grid (1024, nlab), 128 thr. ------
// R11 structure (best measured): 16-row tile (4z x 4y), T=4 sliding y-outs,
// kp[3][37] table, planar bf16 Bu, register-pk ballot compaction, direct
// f32 stores, zero-designation full coverage (no memset). 3-deep pipeline.
template <typename ST>
__global__ __launch_bounds__(128) void pass_yx(const unsigned short* __restrict__ A,
                                               const ST* __restrict__ seg,
                                               float* __restrict__ out,
                                               int label0, size_t a_stride,
                                               Kw kw) {
    __shared__ float kp[3][37];
    __shared__ __align__(16) unsigned short Bu[16 * RSTRIDE]; // 30,976 B
    __shared__ unsigned short lst[LCAP];                      // 1 KB
    __shared__ int cnt;

    // zero Bu (pads must be exactly 0) + weights + counter
    {
        uint4 z4 = make_uint4(0, 0, 0, 0);
        uint4* b4 = (uint4*)Bu;                            // 16*968/8 = 1936
        for (int i = threadIdx.x; i < 1936; i += 128) b4[i] = z4;
    }
    if (threadIdx.x < 37) {
        int i = threadIdx.x, j = i - 3; bool ok = (j >= 0) && (j < KL);
        kp[0][i] = ok ? kw.k0[j] : 0.f;
        kp[1][i] = ok ? kw.k1[j] : 0.f;
        kp[2][i] = ok ? kw.k2[j] : 0.f;
    }
    if (threadIdx.x == 0) cnt = 0;
    __syncthreads();

    const int labi = blockIdx.y;
    const int label = label0 + labi;
    const unsigned short* Ab = A + (size_t)labi * a_stride;
    const int h = blockIdx.x, g = h & 7, l = h >> 3;       // 1024 x-blocks
    const int tx = threadIdx.x & 31, tz = threadIdx.x >> 5; // tz 0..3
    const int x0 = tx * 4;
    const int z0 = 16 * g + 4 * (l & 3);                   // XCD g owns z slab
    const int y0 = (l >> 2) * 4;                           // 32 y-tiles
    const int zs = (z0 + tz) * SLICE;

    // pre-issue compaction seg loads (complete under phase 1)
    const int rr_c = threadIdx.x >> 3, q0_c = threadIdx.x & 7;
    const int vrow_c = ((z0 + (rr_c >> 2)) * 128 + (y0 + (rr_c & 3))) * 128;
    unsigned pk[4];
#pragma unroll
    for (int k = 0; k < 4; ++k)
        pk[k] = seg_pack4(seg + vrow_c + 4 * (q0_c + 8 * k));

    // ---- phase 1: y-conv, T=4 outputs sliding in registers, 3-deep pipe ----
    float4 acc[6][4];                                      // [ch][t]
#pragma unroll
    for (int c = 0; c < 6; ++c)
#pragma unroll
        for (int t = 0; t < 4; ++t) acc[c][t] = make_float4(0.f, 0.f, 0.f, 0.f);

    uint2 a0c = make_uint2(0u, 0u), a1c = a0c, a2c = a0c;  // row j
    uint2 a0n = a0c, a1n = a0c, a2n = a0c;                 // row j+1
    uint2 a0m = a0c, a1m = a0c, a2m = a0c;                 // row j+2
    {
#pragma unroll
        for (int d = 0; d < 3; ++d) {
            int yy = y0 + d - R;
            uint2 u0 = make_uint2(0u, 0u), u1 = u0, u2 = u0;
            if ((unsigned)yy < 128u) {
                int base = zs + yy * 128 + x0;
                u0 = *(const uint2*)(Ab + base);
                u1 = *(const uint2*)(Ab + NV + base);
                u2 = *(const uint2*)(Ab + 2 * NV + base);
            }
            if (d == 0) { a0c = u0; a1c = u1; a2c = u2; }
            else if (d == 1) { a0n = u0; a1n = u1; a2n = u2; }
            else { a0m = u0; a1m = u1; a2m = u2; }
        }
    }
    for (int j = 0; j < 34; ++j) {
        uint2 f0 = make_uint2(0u, 0u), f1 = f0, f2 = f0;
        int yy = y0 + j + 3 - R;
        if (j < 31 && (unsigned)yy < 128u) {
            int base = zs + yy * 128 + x0;
            f0 = *(const uint2*)(Ab + base);
            f1 = *(const uint2*)(Ab + NV + base);
            f2 = *(const uint2*)(Ab + 2 * NV + base);
        }
        float4 a0 = bf4_to_f4(a0c), a1 = bf4_to_f4(a1c), a2 = bf4_to_f4(a2c);
#pragma unroll
        for (int t = 0; t < 4; ++t) {
            int i = j - t + 3;
            float w0 = kp[0][i], w1 = kp[1][i], w2 = kp[2][i];
            fma4(acc[0][t], w0, a0);
            fma4(acc[1][t], w1, a0);
            fma4(acc[2][t], w2, a0);
            fma4(acc[3][t], w0, a1);
            fma4(acc[4][t], w1, a1);
            fma4(acc[5][t], w0, a2);
        }
        a0c = a0n; a1c = a1n; a2c = a2n;
        a0n = a0m; a1n = a1m; a2n = a2m;
        a0m = f0;  a1m = f1;  a2m = f2;
    }
#pragma unroll
    for (int t = 0; t < 4; ++t) {
        const int row = tz * 4 + t;                        // row = 4*zsub + ysub
#pragma unroll
        for (int c = 0; c < 6; ++c) {
            uint2 pv = make_uint2(pack_bf2(acc[c][t].x, acc[c][t].y),
                                  pack_bf2(acc[c][t].z, acc[c][t].w));
            *reinterpret_cast<uint2*>(Bu + row * RSTRIDE + c * CSTRIDE + 16 + x0) = pv;
        }
    }

    // ---- compaction: ballot-based, 1 atomic per wave per step ----
    {
        const int lane = threadIdx.x & 63;
        const unsigned long long below_mask = (1ull << lane) - 1ull;
#pragma unroll
        for (int k = 0; k < 4; ++k) {
            const unsigned w = pk[k];
#pragma unroll
            for (int t = 0; t < 4; ++t) {
                const int sv = (int)((w >> (8 * t)) & 255u);
                const int x = 4 * (q0_c + 8 * k) + t;
                const bool mt = (sv == label);
                const bool zt = !mt && (sv < 1 || sv > 8) &&
                                (((x & 7) + 1) == label);
                const bool pred = mt | zt;
                unsigned long long bal = __ballot(pred);
                int base = 0;
                if (lane == 0 && bal) base = atomicAdd(&cnt, (int)__popcll(bal));
                base = __shfl(base, 0);
                if (pred) {
                    int pos = base + (int)__popcll(bal & below_mask);
                    if (pos < LCAP)
                        lst[pos] = (unsigned short)((rr_c << 7) | x | (zt ? 0x8000 : 0));
                }
            }
        }
    }

    __syncthreads();

    // ---- phase 2: sparse x-conv + epilogue (or zero-store) ----
    const int total = cnt;
    if (total <= LCAP) {
        for (int e = threadIdx.x; e < total; e += 128) {
            int ent = lst[e];
            int rr = (ent >> 7) & 15, x = ent & 127;
            if (ent & 0x8000) zero_voxel(rr, x, z0, y0, out);
            else do_voxel_out(Bu, rr, x, z0, y0, out, kw);
        }
    } else {
        // adversarial-density fallback: dense masked sweep (same math)
        for (int e = threadIdx.x; e < 2048; e += 128) {
            int rr = e >> 7, x = e & 127;
            int z2 = z0 + (rr >> 2), y2 = y0 + (rr & 3);
            int sv = (int)seg[(z2 * 128 + y2) * 128 + x] & 255;
            if (sv == label)
                do_voxel_out(Bu, rr, x, z0, y0, out, kw);
            else if ((sv < 1 || sv > 8) && (((x & 7) + 1) == label))
                zero_voxel(rr, x, z0, y0, out);
        }
    }
}

__global__ __launch_bounds__(256) void seg_to_u8(const int* __restrict__ seg,
                                                 unsigned char* __restrict__ seg8) {
    const int t = blockIdx.x * 256 + threadIdx.x;          // 2048 blocks
    const int4 s = ((const int4*)seg)[t];
    ((uchar4*)seg8)[t] = make_uchar4((unsigned char)s.x, (unsigned char)s.y,
                                     (unsigned char)s.z, (unsigned char)s.w);
}

extern "C" void kernel_launch(void* const* d_in, const int* in_sizes, int n_in,
                              void* d_out, int out_size, void* d_ws, size_t ws_size,
                              hipStream_t stream) {
    const int* seg = (const int*)d_in[0];
    // d_in[1] (coords) unused: math is translation-invariant.
    float* out = (float*)d_out;
    unsigned short* A = (unsigned short*)d_ws;             // bf16 A planes
    const size_t AVOL = (size_t)3 * NV;                    // u16 elements/label

    Kw kw;
    double gg[KL], S = 0.0;
    for (int j = 0; j < KL; ++j) { double d = j - R; gg[j] = exp(-0.5 * d * d / 25.0); S += gg[j]; }
    for (int j = 0; j < KL; ++j) {
        double gn = gg[j] / S, d = j - R;
        kw.k0[j] = (float)gn;
        kw.k1[j] = (float)(-d * gn);   // conv kernel k1 evaluated at (Z - t) = -d
        kw.k2[j] = (float)(d * d * gn);
    }

    // No memset: every output voxel is written exactly once across labels.

    const size_t need_all = 8 * AVOL * sizeof(unsigned short) + NV;  // A_all + seg8
    const size_t need_one = AVOL * sizeof(unsigned short) + NV;

    if (ws_size >= need_all) {
        // 3-dispatch path: labels batched in blockIdx.y, tile-major in x.
        unsigned char* seg8 = (unsigned char*)d_ws + 8 * AVOL * sizeof(unsigned short);
        seg_to_u8<<<dim3(2048), dim3(256), 0, stream>>>(seg, seg8);
        pass_z_t<unsigned char><<<dim3(512, 8), dim3(256), 0, stream>>>(
            seg8, A, 1, AVOL, kw);
        pass_yx<unsigned char><<<dim3(1024, 8), dim3(128), 0, stream>>>(
            A, seg8, out, 1, AVOL, kw);
    } else if (ws_size >= need_one) {
        unsigned char* seg8 = (unsigned char*)d_ws + AVOL * sizeof(unsigned short);
        seg_to_u8<<<dim3(2048), dim3(256), 0, stream>>>(seg, seg8);
        for (int label = 1; label <= 8; ++label) {
            pass_z_t<unsigned char><<<dim3(512, 1), dim3(256), 0, stream>>>(
                seg8, A, label, 0, kw);
            pass_yx<unsigned char><<<dim3(1024, 1), dim3(128), 0, stream>>>(
                A, seg8, out, label, 0, kw);
        }
    } else {
        for (int label = 1; label <= 8; ++label) {
            pass_z_t<int><<<dim3(512, 1), dim3(256), 0, stream>>>(
                seg, A, label, 0, kw);
            pass_yx<int><<<dim3(1024, 1), dim3(128), 0, stream>>>(
                A, seg, out, label, 0, kw);
        }
    }
}

// Round 14
// 401.331 us; speedup vs baseline: 1.0664x; 1.0664x over previous
//
#include <hip/hip_runtime.h>
#include <hip/hip_bf16.h>
#include <math.h>

// LSD (local shape descriptors), 128^3, 8 labels, sigma=5, truncate=3 -> 31-tap kernel.
//
// Algebra: for label mask m, define G_{abc} = (k_a *_z)(k_b *_y)(k_c *_x) m with
//   k0(u)=w(u), k1(u)=u w(u), k2(u)=u^2 w(u)  (w = normalized gaussian).
// At a voxel with mass=G000>0, p=G100/mass, q=G010/mass, s=G001/mass:
//   mean_offset = 0.5 - {p,q,s}/(2 sigma);  cov_ab = (G../mass - ..)/sigma^2.
// Translation-invariant: coords input not needed. Masks disjoint.
//
// Measured record (totals; pass_yx in parens):
//   R11 407 (289, best pass_yx)  R17 405 (302)  R19 423 (302)
//   R20 420 (296)  R21 428 (296; depth-3 refuted)
// Refuted levers: occupancy/TLP (R12-R15,R19,R20), interleaved Bu (R16/R17),
//   full unroll (R18), pipeline depth 3 (R21), weight-table variants (R17).
// UNEXPLAINED counter: WRITE_SIZE 448 MB = 5.3x out (84 MB). Phase-2 rows
//   write ~14 scattered voxels into 8x64B lines; the 8 label-dispatches that
//   would complete each line run ~1024 blocks apart -> L2 evicts partials
//   8x. 448 MB of line-write drain ~ 70-150 us of HBM controller time.
// R22 (this round): label-ADJACENT block order, retry of R9 with the f32->
//   bf16 thrash cure. R9 cut WRITE 417->248 but f32 A made the 8-label halo
//   set 5.9 MB > 4 MB XCD L2 (FETCH 121->400). A is now bf16: halo set
//   0.84 MB << 4 MB. Single change: pass_yx grid (1024,8) -> (8192) with
//   lin = g + 8*lab + 64*tile (XCD = lin&7 kept; a tile's 8 label-blocks
//   are 8 apart -> same XCD, co-resident -> out lines union to 100% ->
//   write amp -> ~1). pass_yx body R11-exact; pass_z the proven 4-x 2-deep.

constexpr int NV = 128 * 128 * 128;
constexpr int SLICE = 128 * 128;
constexpr int R = 15;
constexpr int KL = 31;
constexpr int CSTRIDE = 160;            // u16: 16 pad + 128 data + 16 pad
constexpr int RSTRIDE = 6 * CSTRIDE + 8; // 968 u16; row stagger: 242w = 18 mod 32
constexpr int LCAP = 512;

struct Kw { float k0[KL]; float k1[KL]; float k2[KL]; };

__device__ __forceinline__ void fma4(float4& a, float w, const float4& b) {
    a.x = fmaf(w, b.x, a.x); a.y = fmaf(w, b.y, a.y);
    a.z = fmaf(w, b.z, a.z); a.w = fmaf(w, b.w, a.w);
}

__device__ __forceinline__ float4 load_mask4(const unsigned char* p, int lab) {
    unsigned int u = *(const unsigned int*)p;
    return make_float4(((u       ) & 255u) == (unsigned)lab ? 1.f : 0.f,
                       ((u >>  8 ) & 255u) == (unsigned)lab ? 1.f : 0.f,
                       ((u >> 16 ) & 255u) == (unsigned)lab ? 1.f : 0.f,
                       ((u >> 24 ) & 255u) == (unsigned)lab ? 1.f : 0.f);
}
__device__ __forceinline__ float4 load_mask4(const int* p, int lab) {
    int4 s = *(const int4*)p;
    return make_float4(s.x == lab ? 1.f : 0.f, s.y == lab ? 1.f : 0.f,
                       s.z == lab ? 1.f : 0.f, s.w == lab ? 1.f : 0.f);
}

__device__ __forceinline__ unsigned seg_pack4(const unsigned char* p) {
    return *(const unsigned int*)p;
}
__device__ __forceinline__ unsigned seg_pack4(const int* p) {
    int4 v = *(const int4*)p;
    return (unsigned)(v.x & 255) | ((unsigned)(v.y & 255) << 8) |
           ((unsigned)(v.z & 255) << 16) | ((unsigned)(v.w & 255) << 24);
}

__device__ __forceinline__ float bf_ld(const unsigned short* p) {
    return __uint_as_float(((unsigned int)(*p)) << 16);
}

// 4 packed bf16 (as uint2) -> float4. 1 VALU op per value.
__device__ __forceinline__ float4 bf4_to_f4(uint2 u) {
    return make_float4(__uint_as_float(u.x << 16),
                       __uint_as_float(u.x & 0xFFFF0000u),
                       __uint_as_float(u.y << 16),
                       __uint_as_float(u.y & 0xFFFF0000u));
}

__device__ __forceinline__ unsigned pack_bf2(float a, float b) {
    __hip_bfloat162 h = __float22bfloat162_rn(make_float2(a, b));
    return *reinterpret_cast<unsigned*>(&h);
}

// -------- pass_z: seg -> A[lab][3] bf16 (z-conv). grid (512, nlab), 256 thr.
// Proven R12-R17 form: 4-x threads, 2-deep pipelined window, kp table.
template <typename ST>
__global__ __launch_bounds__(256) void pass_z_t(const ST* __restrict__ seg,
                                                unsigned short* __restrict__ A,
                                                int label0, size_t a_stride,
                                                Kw kw) {
    __shared__ float kp[3][37];           // zero-padded: kp[c][i] = k_c[i-3]
    if (threadIdx.x < 37) {
        int i = threadIdx.x, j = i - 3; bool ok = (j >= 0) && (j < KL);
        kp[0][i] = ok ? kw.k0[j] : 0.f;
        kp[1][i] = ok ? kw.k1[j] : 0.f;
        kp[2][i] = ok ? kw.k2[j] : 0.f;
    }
    __syncthreads();
    const int label = label0 + blockIdx.y;
    unsigned short* Ab = A + (size_t)blockIdx.y * a_stride;
    const int h = blockIdx.x, g = h & 7, l = h >> 3;       // 512 x-blocks
    const int tx = threadIdx.x & 31, ty = threadIdx.x >> 5;
    const int x0 = tx * 4;
    const int z0 = 16 * g + 4 * (l & 3);                   // XCD g owns z [16g,16g+16)
    const int y  = (l >> 2) * 8 + ty;

    float4 acc[4][3];
#pragma unroll
    for (int t = 0; t < 4; ++t)
#pragma unroll
        for (int c = 0; c < 3; ++c) acc[t][c] = make_float4(0.f, 0.f, 0.f, 0.f);

    // 2-deep pipelined sliding window: load j+2 while FMAing j.
    float4 cm = make_float4(0.f, 0.f, 0.f, 0.f), nm = cm;
    {
        int zz = z0 - R;
        if ((unsigned)zz < 128u)
            cm = load_mask4(seg + (zz * SLICE + y * 128 + x0), label);
        int zn = z0 + 1 - R;
        if ((unsigned)zn < 128u)
            nm = load_mask4(seg + (zn * SLICE + y * 128 + x0), label);
    }
    for (int j = 0; j < 34; ++j) {                         // window: 4 outs + 30
        float4 fm = make_float4(0.f, 0.f, 0.f, 0.f);
        int zz = z0 + j + 2 - R;                           // uniform per wave
        if (j < 32 && (unsigned)zz < 128u)
            fm = load_mask4(seg + (zz * SLICE + y * 128 + x0), label);
#pragma unroll
        for (int t = 0; t < 4; ++t) {
            int i = j - t + 3;                             // padded weight index
            fma4(acc[t][0], kp[0][i], cm);
            fma4(acc[t][1], kp[1][i], cm);
            fma4(acc[t][2], kp[2][i], cm);
        }
        cm = nm; nm = fm;
    }
#pragma unroll
    for (int t = 0; t < 4; ++t) {
        int base = (z0 + t) * SLICE + y * 128 + x0;
#pragma unroll
        for (int c = 0; c < 3; ++c) {
            float4 v = acc[t][c];
            uint2 pv = make_uint2(pack_bf2(v.x, v.y), pack_bf2(v.z, v.w));
            *reinterpret_cast<uint2*>(Ab + (size_t)c * NV + base) = pv;
        }
    }
}

// ---- per-voxel sparse x-conv + epilogue (B rows in bf16 LDS, zero-padded) -
__device__ __forceinline__ void conv_voxel(const unsigned short* __restrict__ Bu,
                                           int rr, int x, const Kw& kw,
                                           float o[10]) {
    const unsigned short* row = Bu + rr * RSTRIDE + (x + 1);
    float g000 = 0, g001 = 0, g002 = 0, g010 = 0, g011 = 0,
          g020 = 0, g100 = 0, g101 = 0, g110 = 0, g200 = 0;
#pragma unroll
    for (int j = 0; j < KL; ++j) {
        float w0 = kw.k0[j], w1 = kw.k1[j], w2 = kw.k2[j];
        float b0 = bf_ld(row + 0 * CSTRIDE + j);
        float b1 = bf_ld(row + 1 * CSTRIDE + j);
        float b2 = bf_ld(row + 2 * CSTRIDE + j);
        float b3 = bf_ld(row + 3 * CSTRIDE + j);
        float b4 = bf_ld(row + 4 * CSTRIDE + j);
        float b5 = bf_ld(row + 5 * CSTRIDE + j);
        g000 = fmaf(w0, b0, g000); g001 = fmaf(w1, b0, g001); g002 = fmaf(w2, b0, g002);
        g010 = fmaf(w0, b1, g010); g011 = fmaf(w1, b1, g011);
        g020 = fmaf(w0, b2, g020);
        g100 = fmaf(w0, b3, g100); g101 = fmaf(w1, b3, g101);
        g110 = fmaf(w0, b4, g110);
        g200 = fmaf(w0, b5, g200);
    }
    float mass = g000;
    float denom = (mass > 0.f) ? mass : 1.f;
    float inv = 1.f / denom;
    float p = g100 * inv, q = g010 * inv, s = g001 * inv;
    const float cs = 1.0f / 25.0f;                         // 1/sigma^2
    o[0] = 0.5f - 0.1f * p;                                // 1/(2 sigma) = 0.1
    o[1] = 0.5f - 0.1f * q;
    o[2] = 0.5f - 0.1f * s;
    o[3] = (g200 * inv - p * p) * cs;
    o[4] = (g020 * inv - q * q) * cs;
    o[5] = (g002 * inv - s * s) * cs;
    o[6] = (g110 * inv - p * q) * cs;
    o[7] = (g011 * inv - q * s) * cs;
    o[8] = (g101 * inv - p * s) * cs;
    o[9] = mass;
#pragma unroll
    for (int c = 0; c < 10; ++c) o[c] = fminf(fmaxf(o[c], 0.f), 1.f);
}

__device__ __forceinline__ void do_voxel_out(const unsigned short* __restrict__ Bu,
                                             int rr, int x, int z0, int y0,
                                             float* __restrict__ out, const Kw& kw) {
    float o[10];
    conv_voxel(Bu, rr, x, kw, o);
    const int z2 = z0 + (rr >> 2), y2 = y0 + (rr & 3);
    const int v = (z2 * 128 + y2) * 128 + x;
#pragma unroll
    for (int c = 0; c < 10; ++c) out[(size_t)c * NV + v] = o[c];
}

__device__ __forceinline__ void zero_voxel(int rr, int x, int z0, int y0,
                                           float* __restrict__ out) {
    const int z2 = z0 + (rr >> 2), y2 = y0 + (rr & 3);
    const int v = (z2 * 128 + y2) * 128 + x;
#pragma unroll
    for (int c = 0; c < 10; ++c) out[(size_t)c * NV + v] = 0.f;
}

// -------- pass_yx: A[lab][3] bf16 -> out. 128 thr. -------------------------
// batched=1: grid (8192), lin = g + 8*lab + 64*tile: the 8 label-blocks of a
//   tile share XCD (lin&7) and are launch-adjacent -> out lines union to
//   100% coverage inside L2 before eviction (write amp -> ~1). bf16 A keeps
//   the 8-label halo set at ~0.84 MB << 4 MB XCD L2 (R9's f32 thrash cured).
// batched=0: grid (1024, 1), one label per dispatch (fallback paths).
// Body: R11-exact (best measured 289): 16-row tile (4z x 4y), T=4 sliding
// y-outs, 2-deep pipeline, kp table, planar bf16 Bu, ballot compaction,
// direct f32 stores, zero-designation full coverage (no memset).
template <typename ST>
__global__ __launch_bounds__(128) void pass_yx(const unsigned short* __restrict__ A,
                                               const ST* __restrict__ seg,
                                               float* __restrict__ out,
                                               int label0, size_t a_stride,
                                               Kw kw, int batched) {
    __shared__ float kp[3][37];
    __shared__ __align__(16) unsigned short Bu[16 * RSTRIDE]; // 30,976 B
    __shared__ unsigned short lst[LCAP];                      // 1 KB
    __shared__ int cnt;

    // zero Bu (pads must be exactly 0) + weights + counter
    {
        uint4 z4 = make_uint4(0, 0, 0, 0);
        uint4* b4 = (uint4*)Bu;                            // 16*968/8 = 1936
        for (int i = threadIdx.x; i < 1936; i += 128) b4[i] = z4;
    }
    if (threadIdx.x < 37) {
        int i = threadIdx.x, j = i - 3; bool ok = (j >= 0) && (j < KL);
        kp[0][i] = ok ? kw.k0[j] : 0.f;
        kp[1][i] = ok ? kw.k1[j] : 0.f;
        kp[2][i] = ok ? kw.k2[j] : 0.f;
    }
    if (threadIdx.x == 0) cnt = 0;
    __syncthreads();

    // decode: XCD = b&7 always; batched path interleaves the 8 labels of a
    // tile at stride 8 so they are co-resident on one XCD.
    const int b = blockIdx.x;
    const int g = b & 7;
    int labi, l;
    if (batched) { labi = (b >> 3) & 7; l = b >> 6; }      // 128 tiles/XCD
    else         { labi = 0;            l = b >> 3; }
    const int label = label0 + labi;
    const unsigned short* Ab = A + (size_t)labi * a_stride;
    const int tx = threadIdx.x & 31, tz = threadIdx.x >> 5; // tz 0..3
    const int x0 = tx * 4;
    const int z0 = 16 * g + 4 * (l & 3);                   // XCD g owns z slab
    const int y0 = (l >> 2) * 4;                           // 32 y-tiles
    const int zs = (z0 + tz) * SLICE;

    // pre-issue compaction seg loads (complete under phase 1)
    const int rr_c = threadIdx.x >> 3, q0_c = threadIdx.x & 7;
    const int vrow_c = ((z0 + (rr_c >> 2)) * 128 + (y0 + (rr_c & 3))) * 128;
    unsigned pk[4];
#pragma unroll
    for (int k = 0; k < 4; ++k)
        pk[k] = seg_pack4(seg + vrow_c + 4 * (q0_c + 8 * k));

    // ---- phase 1: y-conv, T=4 outputs sliding in registers, 2-deep pipe ----
    float4 acc[6][4];                                      // [ch][t]
#pragma unroll
    for (int c = 0; c < 6; ++c)
#pragma unroll
        for (int t = 0; t < 4; ++t) acc[c][t] = make_float4(0.f, 0.f, 0.f, 0.f);

    uint2 c0 = make_uint2(0u, 0u), c1 = c0, c2 = c0;       // packed bf16 x4
    uint2 n0 = c0, n1 = c0, n2 = c0;
    {
        int yy = y0 - R;
        if ((unsigned)yy < 128u) {
            int base = zs + yy * 128 + x0;
            c0 = *(const uint2*)(Ab + base);
            c1 = *(const uint2*)(Ab + NV + base);
            c2 = *(const uint2*)(Ab + 2 * NV + base);
        }
        int yn = y0 + 1 - R;
        if ((unsigned)yn < 128u) {
            int base = zs + yn * 128 + x0;
            n0 = *(const uint2*)(Ab + base);
            n1 = *(const uint2*)(Ab + NV + base);
            n2 = *(const uint2*)(Ab + 2 * NV + base);
        }
    }
    for (int j = 0; j < 34; ++j) {
        uint2 f0 = make_uint2(0u, 0u), f1 = f0, f2 = f0;
        int yy = y0 + j + 2 - R;
        if (j < 32 && (unsigned)yy < 128u) {
            int base = zs + yy * 128 + x0;
            f0 = *(const uint2*)(Ab + base);
            f1 = *(const uint2*)(Ab + NV + base);
            f2 = *(const uint2*)(Ab + 2 * NV + base);
        }
        float4 a0 = bf4_to_f4(c0), a1 = bf4_to_f4(c1), a2 = bf4_to_f4(c2);
#pragma unroll
        for (int t = 0; t < 4; ++t) {
            int i = j - t + 3;
            float w0 = kp[0][i], w1 = kp[1][i], w2 = kp[2][i];
            fma4(acc[0][t], w0, a0);
            fma4(acc[1][t], w1, a0);
            fma4(acc[2][t], w2, a0);
            fma4(acc[3][t], w0, a1);
            fma4(acc[4][t], w1, a1);
            fma4(acc[5][t], w0, a2);
        }
        c0 = n0; c1 = n1; c2 = n2;
        n0 = f0; n1 = f1; n2 = f2;
    }
#pragma unroll
    for (int t = 0; t < 4; ++t) {
        const int row = tz * 4 + t;                        // row = 4*zsub + ysub
#pragma unroll
        for (int c = 0; c < 6; ++c) {
            uint2 pv = make_uint2(pack_bf2(acc[c][t].x, acc[c][t].y),
                                  pack_bf2(acc[c][t].z, acc[c][t].w));
            *reinterpret_cast<uint2*>(Bu + row * RSTRIDE + c * CSTRIDE + 16 + x0) = pv;
        }
    }

    // ---- compaction: ballot-based, 1 atomic per wave per step ----
    {
        const int lane = threadIdx.x & 63;
        const unsigned long long below_mask = (1ull << lane) - 1ull;
#pragma unroll
        for (int k = 0; k < 4; ++k) {
            const unsigned w = pk[k];
#pragma unroll
            for (int t = 0; t < 4; ++t) {
                const int sv = (int)((w >> (8 * t)) & 255u);
                const int x = 4 * (q0_c + 8 * k) + t;
                const bool mt = (sv == label);
                const bool zt = !mt && (sv < 1 || sv > 8) &&
                                (((x & 7) + 1) == label);
                const bool pred = mt | zt;
                unsigned long long bal = __ballot(pred);
                int base = 0;
                if (lane == 0 && bal) base = atomicAdd(&cnt, (int)__popcll(bal));
                base = __shfl(base, 0);
                if (pred) {
                    int pos = base + (int)__popcll(bal & below_mask);
                    if (pos < LCAP)
                        lst[pos] = (unsigned short)((rr_c << 7) | x | (zt ? 0x8000 : 0));
                }
            }
        }
    }

    __syncthreads();

    // ---- phase 2: sparse x-conv + epilogue (or zero-store) ----
    const int total = cnt;
    if (total <= LCAP) {
        for (int e = threadIdx.x; e < total; e += 128) {
            int ent = lst[e];
            int rr = (ent >> 7) & 15, x = ent & 127;
            if (ent & 0x8000) zero_voxel(rr, x, z0, y0, out);
            else do_voxel_out(Bu, rr, x, z0, y0, out, kw);
        }
    } else {
        // adversarial-density fallback: dense masked sweep (same math)
        for (int e = threadIdx.x; e < 2048; e += 128) {
            int rr = e >> 7, x = e & 127;
            int z2 = z0 + (rr >> 2), y2 = y0 + (rr & 3);
            int sv = (int)seg[(z2 * 128 + y2) * 128 + x] & 255;
            if (sv == label)
                do_voxel_out(Bu, rr, x, z0, y0, out, kw);
            else if ((sv < 1 || sv > 8) && (((x & 7) + 1) == label))
                zero_voxel(rr, x, z0, y0, out);
        }
    }
}

__global__ __launch_bounds__(256) void seg_to_u8(const int* __restrict__ seg,
                                                 unsigned char* __restrict__ seg8) {
    const int t = blockIdx.x * 256 + threadIdx.x;          // 2048 blocks
    const int4 s = ((const int4*)seg)[t];
    ((uchar4*)seg8)[t] = make_uchar4((unsigned char)s.x, (unsigned char)s.y,
                                     (unsigned char)s.z, (unsigned char)s.w);
}

extern "C" void kernel_launch(void* const* d_in, const int* in_sizes, int n_in,
                              void* d_out, int out_size, void* d_ws, size_t ws_size,
                              hipStream_t stream) {
    const int* seg = (const int*)d_in[0];
    // d_in[1] (coords) unused: math is translation-invariant.
    float* out = (float*)d_out;
    unsigned short* A = (unsigned short*)d_ws;             // bf16 A planes
    const size_t AVOL = (size_t)3 * NV;                    // u16 elements/label

    Kw kw;
    double gg[KL], S = 0.0;
    for (int j = 0; j < KL; ++j) { double d = j - R; gg[j] = exp(-0.5 * d * d / 25.0); S += gg[j]; }
    for (int j = 0; j < KL; ++j) {
        double gn = gg[j] / S, d = j - R;
        kw.k0[j] = (float)gn;
        kw.k1[j] = (float)(-d * gn);   // conv kernel k1 evaluated at (Z - t) = -d
        kw.k2[j] = (float)(d * d * gn);
    }

    // No memset: every output voxel is written exactly once across labels.

    const size_t need_all = 8 * AVOL * sizeof(unsigned short) + NV;  // A_all + seg8
    const size_t need_one = AVOL * sizeof(unsigned short) + NV;

    if (ws_size >= need_all) {
        // 3-dispatch path: label-adjacent linearization in pass_yx.
        unsigned char* seg8 = (unsigned char*)d_ws + 8 * AVOL * sizeof(unsigned short);
        seg_to_u8<<<dim3(2048), dim3(256), 0, stream>>>(seg, seg8);
        pass_z_t<unsigned char><<<dim3(512, 8), dim3(256), 0, stream>>>(
            seg8, A, 1, AVOL, kw);
        pass_yx<unsigned char><<<dim3(8192, 1), dim3(128), 0, stream>>>(
            A, seg8, out, 1, AVOL, kw, 1);
    } else if (ws_size >= need_one) {
        unsigned char* seg8 = (unsigned char*)d_ws + AVOL * sizeof(unsigned short);
        seg_to_u8<<<dim3(2048), dim3(256), 0, stream>>>(seg, seg8);
        for (int label = 1; label <= 8; ++label) {
            pass_z_t<unsigned char><<<dim3(512, 1), dim3(256), 0, stream>>>(
                seg8, A, label, 0, kw);
            pass_yx<unsigned char><<<dim3(1024, 1), dim3(128), 0, stream>>>(
                A, seg8, out, label, 0, kw, 0);
        }
    } else {
        for (int label = 1; label <= 8; ++label) {
            pass_z_t<int><<<dim3(512, 1), dim3(256), 0, stream>>>(
                seg, A, label, 0, kw);
            pass_yx<int><<<dim3(1024, 1), dim3(128), 0, stream>>>(
                A, seg, out, label, 0, kw, 0);
        }
    }
}

// Round 15
// 385.112 us; speedup vs baseline: 1.1113x; 1.0421x over previous
//
#include <hip/hip_runtime.h>
#include <hip/hip_bf16.h>
#include <math.h>

// LSD (local shape descriptors), 128^3, 8 labels, sigma=5, truncate=3 -> 31-tap kernel.
//
// Algebra: for label mask m, define G_{abc} = (k_a *_z)(k_b *_y)(k_c *_x) m with
//   k0(u)=w(u), k1(u)=u w(u), k2(u)=u^2 w(u)  (w = normalized gaussian).
// At a voxel with mass=G000>0, p=G100/mass, q=G010/mass, s=G001/mass:
//   mean_offset = 0.5 - {p,q,s}/(2 sigma);  cov_ab = (G../mass - ..)/sigma^2.
// Translation-invariant: coords input not needed. Masks disjoint.
//
// Measured record (totals; pass_yx in parens):
//   R11 407 (289)  R17 405 (302)  R20 420 (296)  R21 428 (296)
//   R22 401 (279, BEST): label-adjacent lin = g+8*lab+64*l -> the 8 label
//   blocks of a tile co-resident on one XCD -> out lines union -> WRITE
//   448->138 MB; ~17 us win. BUT FETCH 59->206 MB: same-label y-neighbor
//   tiles now 32 blocks apart; two-y-group 8-label halo set 6.6 MB > 4 MB
//   XCD L2 -> halo loads miss to HBM (~900cy > 516cy pipeline cover).
// R23 (this round): one-line decode swap, l = (zsub<<5)|ytile (was
//   (ytile<<2)|zsub). ytile now varies fastest per XCD: consecutive
//   y-tiles of one z-slab are 8 blocks apart; halo set 0.84 MB << 4 MB ->
//   L2 hits (~200cy, covered by 2-deep pipeline). Label-adjacency (stride
//   8) untouched -> write-merge preserved. Everything else R22-identical.

constexpr int NV = 128 * 128 * 128;
constexpr int SLICE = 128 * 128;
constexpr int R = 15;
constexpr int KL = 31;
constexpr int CSTRIDE = 160;            // u16: 16 pad + 128 data + 16 pad
constexpr int RSTRIDE = 6 * CSTRIDE + 8; // 968 u16; row stagger: 242w = 18 mod 32
constexpr int LCAP = 512;

struct Kw { float k0[KL]; float k1[KL]; float k2[KL]; };

__device__ __forceinline__ void fma4(float4& a, float w, const float4& b) {
    a.x = fmaf(w, b.x, a.x); a.y = fmaf(w, b.y, a.y);
    a.z = fmaf(w, b.z, a.z); a.w = fmaf(w, b.w, a.w);
}

__device__ __forceinline__ float4 load_mask4(const unsigned char* p, int lab) {
    unsigned int u = *(const unsigned int*)p;
    return make_float4(((u       ) & 255u) == (unsigned)lab ? 1.f : 0.f,
                       ((u >>  8 ) & 255u) == (unsigned)lab ? 1.f : 0.f,
                       ((u >> 16 ) & 255u) == (unsigned)lab ? 1.f : 0.f,
                       ((u >> 24 ) & 255u) == (unsigned)lab ? 1.f : 0.f);
}
__device__ __forceinline__ float4 load_mask4(const int* p, int lab) {
    int4 s = *(const int4*)p;
    return make_float4(s.x == lab ? 1.f : 0.f, s.y == lab ? 1.f : 0.f,
                       s.z == lab ? 1.f : 0.f, s.w == lab ? 1.f : 0.f);
}

__device__ __forceinline__ unsigned seg_pack4(const unsigned char* p) {
    return *(const unsigned int*)p;
}
__device__ __forceinline__ unsigned seg_pack4(const int* p) {
    int4 v = *(const int4*)p;
    return (unsigned)(v.x & 255) | ((unsigned)(v.y & 255) << 8) |
           ((unsigned)(v.z & 255) << 16) | ((unsigned)(v.w & 255) << 24);
}

__device__ __forceinline__ float bf_ld(const unsigned short* p) {
    return __uint_as_float(((unsigned int)(*p)) << 16);
}

// 4 packed bf16 (as uint2) -> float4. 1 VALU op per value.
__device__ __forceinline__ float4 bf4_to_f4(uint2 u) {
    return make_float4(__uint_as_float(u.x << 16),
                       __uint_as_float(u.x & 0xFFFF0000u),
                       __uint_as_float(u.y << 16),
                       __uint_as_float(u.y & 0xFFFF0000u));
}

__device__ __forceinline__ unsigned pack_bf2(float a, float b) {
    __hip_bfloat162 h = __float22bfloat162_rn(make_float2(a, b));
    return *reinterpret_cast<unsigned*>(&h);
}

// -------- pass_z: seg -> A[lab][3] bf16 (z-conv). grid (512, nlab), 256 thr.
// Proven form: 4-x threads, 2-deep pipelined window, kp table.
template <typename ST>
__global__ __launch_bounds__(256) void pass_z_t(const ST* __restrict__ seg,
                                                unsigned short* __restrict__ A,
                                                int label0, size_t a_stride,
                                                Kw kw) {
    __shared__ float kp[3][37];           // zero-padded: kp[c][i] = k_c[i-3]
    if (threadIdx.x < 37) {
        int i = threadIdx.x, j = i - 3; bool ok = (j >= 0) && (j < KL);
        kp[0][i] = ok ? kw.k0[j] : 0.f;
        kp[1][i] = ok ? kw.k1[j] : 0.f;
        kp[2][i] = ok ? kw.k2[j] : 0.f;
    }
    __syncthreads();
    const int label = label0 + blockIdx.y;
    unsigned short* Ab = A + (size_t)blockIdx.y * a_stride;
    const int h = blockIdx.x, g = h & 7, l = h >> 3;       // 512 x-blocks
    const int tx = threadIdx.x & 31, ty = threadIdx.x >> 5;
    const int x0 = tx * 4;
    const int z0 = 16 * g + 4 * (l & 3);                   // XCD g owns z [16g,16g+16)
    const int y  = (l >> 2) * 8 + ty;

    float4 acc[4][3];
#pragma unroll
    for (int t = 0; t < 4; ++t)
#pragma unroll
        for (int c = 0; c < 3; ++c) acc[t][c] = make_float4(0.f, 0.f, 0.f, 0.f);

    // 2-deep pipelined sliding window: load j+2 while FMAing j.
    float4 cm = make_float4(0.f, 0.f, 0.f, 0.f), nm = cm;
    {
        int zz = z0 - R;
        if ((unsigned)zz < 128u)
            cm = load_mask4(seg + (zz * SLICE + y * 128 + x0), label);
        int zn = z0 + 1 - R;
        if ((unsigned)zn < 128u)
            nm = load_mask4(seg + (zn * SLICE + y * 128 + x0), label);
    }
    for (int j = 0; j < 34; ++j) {                         // window: 4 outs + 30
        float4 fm = make_float4(0.f, 0.f, 0.f, 0.f);
        int zz = z0 + j + 2 - R;                           // uniform per wave
        if (j < 32 && (unsigned)zz < 128u)
            fm = load_mask4(seg + (zz * SLICE + y * 128 + x0), label);
#pragma unroll
        for (int t = 0; t < 4; ++t) {
            int i = j - t + 3;                             // padded weight index
            fma4(acc[t][0], kp[0][i], cm);
            fma4(acc[t][1], kp[1][i], cm);
            fma4(acc[t][2], kp[2][i], cm);
        }
        cm = nm; nm = fm;
    }
#pragma unroll
    for (int t = 0; t < 4; ++t) {
        int base = (z0 + t) * SLICE + y * 128 + x0;
#pragma unroll
        for (int c = 0; c < 3; ++c) {
            float4 v = acc[t][c];
            uint2 pv = make_uint2(pack_bf2(v.x, v.y), pack_bf2(v.z, v.w));
            *reinterpret_cast<uint2*>(Ab + (size_t)c * NV + base) = pv;
        }
    }
}

// ---- per-voxel sparse x-conv + epilogue (B rows in bf16 LDS, zero-padded) -
__device__ __forceinline__ void conv_voxel(const unsigned short* __restrict__ Bu,
                                           int rr, int x, const Kw& kw,
                                           float o[10]) {
    const unsigned short* row = Bu + rr * RSTRIDE + (x + 1);
    float g000 = 0, g001 = 0, g002 = 0, g010 = 0, g011 = 0,
          g020 = 0, g100 = 0, g101 = 0, g110 = 0, g200 = 0;
#pragma unroll
    for (int j = 0; j < KL; ++j) {
        float w0 = kw.k0[j], w1 = kw.k1[j], w2 = kw.k2[j];
        float b0 = bf_ld(row + 0 * CSTRIDE + j);
        float b1 = bf_ld(row + 1 * CSTRIDE + j);
        float b2 = bf_ld(row + 2 * CSTRIDE + j);
        float b3 = bf_ld(row + 3 * CSTRIDE + j);
        float b4 = bf_ld(row + 4 * CSTRIDE + j);
        float b5 = bf_ld(row + 5 * CSTRIDE + j);
        g000 = fmaf(w0, b0, g000); g001 = fmaf(w1, b0, g001); g002 = fmaf(w2, b0, g002);
        g010 = fmaf(w0, b1, g010); g011 = fmaf(w1, b1, g011);
        g020 = fmaf(w0, b2, g020);
        g100 = fmaf(w0, b3, g100); g101 = fmaf(w1, b3, g101);
        g110 = fmaf(w0, b4, g110);
        g200 = fmaf(w0, b5, g200);
    }
    float mass = g000;
    float denom = (mass > 0.f) ? mass : 1.f;
    float inv = 1.f / denom;
    float p = g100 * inv, q = g010 * inv, s = g001 * inv;
    const float cs = 1.0f / 25.0f;                         // 1/sigma^2
    o[0] = 0.5f - 0.1f * p;                                // 1/(2 sigma) = 0.1
    o[1] = 0.5f - 0.1f * q;
    o[2] = 0.5f - 0.1f * s;
    o[3] = (g200 * inv - p * p) * cs;
    o[4] = (g020 * inv - q * q) * cs;
    o[5] = (g002 * inv - s * s) * cs;
    o[6] = (g110 * inv - p * q) * cs;
    o[7] = (g011 * inv - q * s) * cs;
    o[8] = (g101 * inv - p * s) * cs;
    o[9] = mass;
#pragma unroll
    for (int c = 0; c < 10; ++c) o[c] = fminf(fmaxf(o[c], 0.f), 1.f);
}

__device__ __forceinline__ void do_voxel_out(const unsigned short* __restrict__ Bu,
                                             int rr, int x, int z0, int y0,
                                             float* __restrict__ out, const Kw& kw) {
    float o[10];
    conv_voxel(Bu, rr, x, kw, o);
    const int z2 = z0 + (rr >> 2), y2 = y0 + (rr & 3);
    const int v = (z2 * 128 + y2) * 128 + x;
#pragma unroll
    for (int c = 0; c < 10; ++c) out[(size_t)c * NV + v] = o[c];
}

__device__ __forceinline__ void zero_voxel(int rr, int x, int z0, int y0,
                                           float* __restrict__ out) {
    const int z2 = z0 + (rr >> 2), y2 = y0 + (rr & 3);
    const int v = (z2 * 128 + y2) * 128 + x;
#pragma unroll
    for (int c = 0; c < 10; ++c) out[(size_t)c * NV + v] = 0.f;
}

// -------- pass_yx: A[lab][3] bf16 -> out. 128 thr. -------------------------
// batched=1: grid (8192), lin = g + 8*lab + 64*l with l = (zsub<<5)|ytile:
//   - the 8 label-blocks of a tile share XCD (lin&7) and are adjacent ->
//     out lines union to 100% in L2 (write amp ~1; R22-proven).
//   - ytile varies fastest -> same-label y-neighbor tiles 8 blocks apart ->
//     0.84 MB halo set << 4 MB XCD L2 -> A halo loads are L2 hits, covered
//     by the 2-deep pipeline (R23 change).
// batched=0: grid (1024, 1), one label per dispatch (fallback paths).
// Body: R11-exact: 16-row tile (4z x 4y), T=4 sliding y-outs, 2-deep
// pipeline, kp table, planar bf16 Bu, ballot compaction, direct f32 stores,
// zero-designation full coverage (no memset).
template <typename ST>
__global__ __launch_bounds__(128) void pass_yx(const unsigned short* __restrict__ A,
                                               const ST* __restrict__ seg,
                                               float* __restrict__ out,
                                               int label0, size_t a_stride,
                                               Kw kw, int batched) {
    __shared__ float kp[3][37];
    __shared__ __align__(16) unsigned short Bu[16 * RSTRIDE]; // 30,976 B
    __shared__ unsigned short lst[LCAP];                      // 1 KB
    __shared__ int cnt;

    // zero Bu (pads must be exactly 0) + weights + counter
    {
        uint4 z4 = make_uint4(0, 0, 0, 0);
        uint4* b4 = (uint4*)Bu;                            // 16*968/8 = 1936
        for (int i = threadIdx.x; i < 1936; i += 128) b4[i] = z4;
    }
    if (threadIdx.x < 37) {
        int i = threadIdx.x, j = i - 3; bool ok = (j >= 0) && (j < KL);
        kp[0][i] = ok ? kw.k0[j] : 0.f;
        kp[1][i] = ok ? kw.k1[j] : 0.f;
        kp[2][i] = ok ? kw.k2[j] : 0.f;
    }
    if (threadIdx.x == 0) cnt = 0;
    __syncthreads();

    // decode: XCD = b&7 always; batched path interleaves the 8 labels of a
    // tile at stride 8; within an XCD, ytile varies fastest (halo L2 reuse).
    const int b = blockIdx.x;
    const int g = b & 7;
    int labi, l;
    if (batched) { labi = (b >> 3) & 7; l = b >> 6; }      // 128 tiles/XCD
    else         { labi = 0;            l = b >> 3; }
    const int zsub = l >> 5, ytile = l & 31;               // ytile fastest
    const int label = label0 + labi;
    const unsigned short* Ab = A + (size_t)labi * a_stride;
    const int tx = threadIdx.x & 31, tz = threadIdx.x >> 5; // tz 0..3
    const int x0 = tx * 4;
    const int z0 = 16 * g + 4 * zsub;                      // XCD g owns z slab
    const int y0 = ytile * 4;                              // 32 y-tiles
    const int zs = (z0 + tz) * SLICE;

    // pre-issue compaction seg loads (complete under phase 1)
    const int rr_c = threadIdx.x >> 3, q0_c = threadIdx.x & 7;
    const int vrow_c = ((z0 + (rr_c >> 2)) * 128 + (y0 + (rr_c & 3))) * 128;
    unsigned pk[4];
#pragma unroll
    for (int k = 0; k < 4; ++k)
        pk[k] = seg_pack4(seg + vrow_c + 4 * (q0_c + 8 * k));

    // ---- phase 1: y-conv, T=4 outputs sliding in registers, 2-deep pipe ----
    float4 acc[6][4];                                      // [ch][t]
#pragma unroll
    for (int c = 0; c < 6; ++c)
#pragma unroll
        for (int t = 0; t < 4; ++t) acc[c][t] = make_float4(0.f, 0.f, 0.f, 0.f);

    uint2 c0 = make_uint2(0u, 0u), c1 = c0, c2 = c0;       // packed bf16 x4
    uint2 n0 = c0, n1 = c0, n2 = c0;
    {
        int yy = y0 - R;
        if ((unsigned)yy < 128u) {
            int base = zs + yy * 128 + x0;
            c0 = *(const uint2*)(Ab + base);
            c1 = *(const uint2*)(Ab + NV + base);
            c2 = *(const uint2*)(Ab + 2 * NV + base);
        }
        int yn = y0 + 1 - R;
        if ((unsigned)yn < 128u) {
            int base = zs + yn * 128 + x0;
            n0 = *(const uint2*)(Ab + base);
            n1 = *(const uint2*)(Ab + NV + base);
            n2 = *(const uint2*)(Ab + 2 * NV + base);
        }
    }
    for (int j = 0; j < 34; ++j) {
        uint2 f0 = make_uint2(0u, 0u), f1 = f0, f2 = f0;
        int yy = y0 + j + 2 - R;
        if (j < 32 && (unsigned)yy < 128u) {
            int base = zs + yy * 128 + x0;
            f0 = *(const uint2*)(Ab + base);
            f1 = *(const uint2*)(Ab + NV + base);
            f2 = *(const uint2*)(Ab + 2 * NV + base);
        }
        float4 a0 = bf4_to_f4(c0), a1 = bf4_to_f4(c1), a2 = bf4_to_f4(c2);
#pragma unroll
        for (int t = 0; t < 4; ++t) {
            int i = j - t + 3;
            float w0 = kp[0][i], w1 = kp[1][i], w2 = kp[2][i];
            fma4(acc[0][t], w0, a0);
            fma4(acc[1][t], w1, a0);
            fma4(acc[2][t], w2, a0);
            fma4(acc[3][t], w0, a1);
            fma4(acc[4][t], w1, a1);
            fma4(acc[5][t], w0, a2);
        }
        c0 = n0; c1 = n1; c2 = n2;
        n0 = f0; n1 = f1; n2 = f2;
    }
#pragma unroll
    for (int t = 0; t < 4; ++t) {
        const int row = tz * 4 + t;                        // row = 4*zsub + ysub
#pragma unroll
        for (int c = 0; c < 6; ++c) {
            uint2 pv = make_uint2(pack_bf2(acc[c][t].x, acc[c][t].y),
                                  pack_bf2(acc[c][t].z, acc[c][t].w));
            *reinterpret_cast<uint2*>(Bu + row * RSTRIDE + c * CSTRIDE + 16 + x0) = pv;
        }
    }

    // ---- compaction: ballot-based, 1 atomic per wave per step ----
    {
        const int lane = threadIdx.x & 63;
        const unsigned long long below_mask = (1ull << lane) - 1ull;
#pragma unroll
        for (int k = 0; k < 4; ++k) {
            const unsigned w = pk[k];
#pragma unroll
            for (int t = 0; t < 4; ++t) {
                const int sv = (int)((w >> (8 * t)) & 255u);
                const int x = 4 * (q0_c + 8 * k) + t;
                const bool mt = (sv == label);
                const bool zt = !mt && (sv < 1 || sv > 8) &&
                                (((x & 7) + 1) == label);
                const bool pred = mt | zt;
                unsigned long long bal = __ballot(pred);
                int base = 0;
                if (lane == 0 && bal) base = atomicAdd(&cnt, (int)__popcll(bal));
                base = __shfl(base, 0);
                if (pred) {
                    int pos = base + (int)__popcll(bal & below_mask);
                    if (pos < LCAP)
                        lst[pos] = (unsigned short)((rr_c << 7) | x | (zt ? 0x8000 : 0));
                }
            }
        }
    }

    __syncthreads();

    // ---- phase 2: sparse x-conv + epilogue (or zero-store) ----
    const int total = cnt;
    if (total <= LCAP) {
        for (int e = threadIdx.x; e < total; e += 128) {
            int ent = lst[e];
            int rr = (ent >> 7) & 15, x = ent & 127;
            if (ent & 0x8000) zero_voxel(rr, x, z0, y0, out);
            else do_voxel_out(Bu, rr, x, z0, y0, out, kw);
        }
    } else {
        // adversarial-density fallback: dense masked sweep (same math)
        for (int e = threadIdx.x; e < 2048; e += 128) {
            int rr = e >> 7, x = e & 127;
            int z2 = z0 + (rr >> 2), y2 = y0 + (rr & 3);
            int sv = (int)seg[(z2 * 128 + y2) * 128 + x] & 255;
            if (sv == label)
                do_voxel_out(Bu, rr, x, z0, y0, out, kw);
            else if ((sv < 1 || sv > 8) && (((x & 7) + 1) == label))
                zero_voxel(rr, x, z0, y0, out);
        }
    }
}

__global__ __launch_bounds__(256) void seg_to_u8(const int* __restrict__ seg,
                                                 unsigned char* __restrict__ seg8) {
    const int t = blockIdx.x * 256 + threadIdx.x;          // 2048 blocks
    const int4 s = ((const int4*)seg)[t];
    ((uchar4*)seg8)[t] = make_uchar4((unsigned char)s.x, (unsigned char)s.y,
                                     (unsigned char)s.z, (unsigned char)s.w);
}

extern "C" void kernel_launch(void* const* d_in, const int* in_sizes, int n_in,
                              void* d_out, int out_size, void* d_ws, size_t ws_size,
                              hipStream_t stream) {
    const int* seg = (const int*)d_in[0];
    // d_in[1] (coords) unused: math is translation-invariant.
    float* out = (float*)d_out;
    unsigned short* A = (unsigned short*)d_ws;             // bf16 A planes
    const size_t AVOL = (size_t)3 * NV;                    // u16 elements/label

    Kw kw;
    double gg[KL], S = 0.0;
    for (int j = 0; j < KL; ++j) { double d = j - R; gg[j] = exp(-0.5 * d * d / 25.0); S += gg[j]; }
    for (int j = 0; j < KL; ++j) {
        double gn = gg[j] / S, d = j - R;
        kw.k0[j] = (float)gn;
        kw.k1[j] = (float)(-d * gn);   // conv kernel k1 evaluated at (Z - t) = -d
        kw.k2[j] = (float)(d * d * gn);
    }

    // No memset: every output voxel is written exactly once across labels.

    const size_t need_all = 8 * AVOL * sizeof(unsigned short) + NV;  // A_all + seg8
    const size_t need_one = AVOL * sizeof(unsigned short) + NV;

    if (ws_size >= need_all) {
        // 3-dispatch path: label-adjacent linearization in pass_yx.
        unsigned char* seg8 = (unsigned char*)d_ws + 8 * AVOL * sizeof(unsigned short);
        seg_to_u8<<<dim3(2048), dim3(256), 0, stream>>>(seg, seg8);
        pass_z_t<unsigned char><<<dim3(512, 8), dim3(256), 0, stream>>>(
            seg8, A, 1, AVOL, kw);
        pass_yx<unsigned char><<<dim3(8192, 1), dim3(128), 0, stream>>>(
            A, seg8, out, 1, AVOL, kw, 1);
    } else if (ws_size >= need_one) {
        unsigned char* seg8 = (unsigned char*)d_ws + AVOL * sizeof(unsigned short);
        seg_to_u8<<<dim3(2048), dim3(256), 0, stream>>>(seg, seg8);
        for (int label = 1; label <= 8; ++label) {
            pass_z_t<unsigned char><<<dim3(512, 1), dim3(256), 0, stream>>>(
                seg8, A, label, 0, kw);
            pass_yx<unsigned char><<<dim3(1024, 1), dim3(128), 0, stream>>>(
                A, seg8, out, label, 0, kw, 0);
        }
    } else {
        for (int label = 1; label <= 8; ++label) {
            pass_z_t<int><<<dim3(512, 1), dim3(256), 0, stream>>>(
                seg, A, label, 0, kw);
            pass_yx<int><<<dim3(1024, 1), dim3(128), 0, stream>>>(
                A, seg, out, label, 0, kw, 0);
        }
    }
}

// Round 16
// 373.036 us; speedup vs baseline: 1.1473x; 1.0324x over previous
//
#include <hip/hip_runtime.h>
#include <hip/hip_bf16.h>
#include <math.h>

// LSD (local shape descriptors), 128^3, 8 labels, sigma=5, truncate=3 -> 31-tap kernel.
//
// Algebra: for label mask m, define G_{abc} = (k_a *_z)(k_b *_y)(k_c *_x) m with
//   k0(u)=w(u), k1(u)=u w(u), k2(u)=u^2 w(u)  (w = normalized gaussian).
// At a voxel with mass=G000>0, p=G100/mass, q=G010/mass, s=G001/mass:
//   mean_offset = 0.5 - {p,q,s}/(2 sigma);  cov_ab = (G../mass - ..)/sigma^2.
// Translation-invariant: coords input not needed. Masks disjoint.
//
// Measured record (totals; pass_yx in parens):
//   R11 407 (289)  R17 405 (302)  R22 401 (279)  R23 385 (265, BEST):
//   label-adjacent lin g+8*lab+64*l with l=(zsub<<5)|ytile -> write-merge
//   (WRITE 448->91 MB, amp ~1) AND y-halo L2 reuse (FETCH 206->50 MB).
//   Traffic now near-compulsory; VALUBusy 52.7%, occ 21%. Remaining 265 us
//   ~ 139 us VALU issue + stall. Occupancy/TLP refuted; traffic solved ->
//   the last causal lever is ISSUE COUNT.
// R24 (this round): packed-FP32 FMAs. CDNA4 v_pk_fma_f32 = 2 FMA/instr
//   (full-rate; scalar v_fma is half the 157TF peak). clang lowers
//   __builtin_elementwise_fma on ext_vector float2 to v_pk_fma_f32.
//   - pass_yx phase 1: 96 scalar FMA/iter -> 48 pk (acc in lo/hi v2f).
//   - phase 2: (g000,g001),(g010,g011),(g100,g101) as v2f pairs with
//     broadcast b: 10 -> 3 pk + 4 scalar per tap.
//   - pass_z: 48 FMA/iter -> 24 pk.
//   Worst case compiler scalarizes -> identical code (neutral). Structure
//   otherwise R23-byte-identical.

constexpr int NV = 128 * 128 * 128;
constexpr int SLICE = 128 * 128;
constexpr int R = 15;
constexpr int KL = 31;
constexpr int CSTRIDE = 160;            // u16: 16 pad + 128 data + 16 pad
constexpr int RSTRIDE = 6 * CSTRIDE + 8; // 968 u16; row stagger: 242w = 18 mod 32
constexpr int LCAP = 512;

struct Kw { float k0[KL]; float k1[KL]; float k2[KL]; };

typedef float v2f __attribute__((ext_vector_type(2)));

__device__ __forceinline__ v2f pfma(v2f w, v2f b, v2f acc) {
    return __builtin_elementwise_fma(w, b, acc);
}

__device__ __forceinline__ float4 load_mask4(const unsigned char* p, int lab) {
    unsigned int u = *(const unsigned int*)p;
    return make_float4(((u       ) & 255u) == (unsigned)lab ? 1.f : 0.f,
                       ((u >>  8 ) & 255u) == (unsigned)lab ? 1.f : 0.f,
                       ((u >> 16 ) & 255u) == (unsigned)lab ? 1.f : 0.f,
                       ((u >> 24 ) & 255u) == (unsigned)lab ? 1.f : 0.f);
}
__device__ __forceinline__ float4 load_mask4(const int* p, int lab) {
    int4 s = *(const int4*)p;
    return make_float4(s.x == lab ? 1.f : 0.f, s.y == lab ? 1.f : 0.f,
                       s.z == lab ? 1.f : 0.f, s.w == lab ? 1.f : 0.f);
}

__device__ __forceinline__ unsigned seg_pack4(const unsigned char* p) {
    return *(const unsigned int*)p;
}
__device__ __forceinline__ unsigned seg_pack4(const int* p) {
    int4 v = *(const int4*)p;
    return (unsigned)(v.x & 255) | ((unsigned)(v.y & 255) << 8) |
           ((unsigned)(v.z & 255) << 16) | ((unsigned)(v.w & 255) << 24);
}

__device__ __forceinline__ float bf_ld(const unsigned short* p) {
    return __uint_as_float(((unsigned int)(*p)) << 16);
}

// packed bf16 pair (u32) -> v2f {lo, hi}. 1 VALU op per value.
__device__ __forceinline__ v2f bf2_v(unsigned u) {
    v2f r;
    r.x = __uint_as_float(u << 16);
    r.y = __uint_as_float(u & 0xFFFF0000u);
    return r;
}

__device__ __forceinline__ unsigned pack_bf2(float a, float b) {
    __hip_bfloat162 h = __float22bfloat162_rn(make_float2(a, b));
    return *reinterpret_cast<unsigned*>(&h);
}

// -------- pass_z: seg -> A[lab][3] bf16 (z-conv). grid (512, nlab), 256 thr.
// Proven form: 4-x threads, 2-deep pipelined window, kp table, pk-FMA.
template <typename ST>
__global__ __launch_bounds__(256) void pass_z_t(const ST* __restrict__ seg,
                                                unsigned short* __restrict__ A,
                                                int label0, size_t a_stride,
                                                Kw kw) {
    __shared__ float kp[3][37];           // zero-padded: kp[c][i] = k_c[i-3]
    if (threadIdx.x < 37) {
        int i = threadIdx.x, j = i - 3; bool ok = (j >= 0) && (j < KL);
        kp[0][i] = ok ? kw.k0[j] : 0.f;
        kp[1][i] = ok ? kw.k1[j] : 0.f;
        kp[2][i] = ok ? kw.k2[j] : 0.f;
    }
    __syncthreads();
    const int label = label0 + blockIdx.y;
    unsigned short* Ab = A + (size_t)blockIdx.y * a_stride;
    const int h = blockIdx.x, g = h & 7, l = h >> 3;       // 512 x-blocks
    const int tx = threadIdx.x & 31, ty = threadIdx.x >> 5;
    const int x0 = tx * 4;
    const int z0 = 16 * g + 4 * (l & 3);                   // XCD g owns z [16g,16g+16)
    const int y  = (l >> 2) * 8 + ty;

    v2f accL[4][3], accH[4][3];
#pragma unroll
    for (int t = 0; t < 4; ++t)
#pragma unroll
        for (int c = 0; c < 3; ++c) { accL[t][c] = (v2f)(0.f); accH[t][c] = (v2f)(0.f); }

    // 2-deep pipelined sliding window: load j+2 while FMAing j.
    float4 cm = make_float4(0.f, 0.f, 0.f, 0.f), nm = cm;
    {
        int zz = z0 - R;
        if ((unsigned)zz < 128u)
            cm = load_mask4(seg + (zz * SLICE + y * 128 + x0), label);
        int zn = z0 + 1 - R;
        if ((unsigned)zn < 128u)
            nm = load_mask4(seg + (zn * SLICE + y * 128 + x0), label);
    }
    for (int j = 0; j < 34; ++j) {                         // window: 4 outs + 30
        float4 fm = make_float4(0.f, 0.f, 0.f, 0.f);
        int zz = z0 + j + 2 - R;                           // uniform per wave
        if (j < 32 && (unsigned)zz < 128u)
            fm = load_mask4(seg + (zz * SLICE + y * 128 + x0), label);
        v2f cl = {cm.x, cm.y}, ch = {cm.z, cm.w};
#pragma unroll
        for (int t = 0; t < 4; ++t) {
            int i = j - t + 3;                             // padded weight index
            v2f W0 = (v2f)(kp[0][i]);
            v2f W1 = (v2f)(kp[1][i]);
            v2f W2 = (v2f)(kp[2][i]);
            accL[t][0] = pfma(W0, cl, accL[t][0]); accH[t][0] = pfma(W0, ch, accH[t][0]);
            accL[t][1] = pfma(W1, cl, accL[t][1]); accH[t][1] = pfma(W1, ch, accH[t][1]);
            accL[t][2] = pfma(W2, cl, accL[t][2]); accH[t][2] = pfma(W2, ch, accH[t][2]);
        }
        cm = nm; nm = fm;
    }
#pragma unroll
    for (int t = 0; t < 4; ++t) {
        int base = (z0 + t) * SLICE + y * 128 + x0;
#pragma unroll
        for (int c = 0; c < 3; ++c) {
            uint2 pv = make_uint2(pack_bf2(accL[t][c].x, accL[t][c].y),
                                  pack_bf2(accH[t][c].x, accH[t][c].y));
            *reinterpret_cast<uint2*>(Ab + (size_t)c * NV + base) = pv;
        }
    }
}

// ---- per-voxel sparse x-conv + epilogue (B rows in bf16 LDS, zero-padded) -
// Packed pairs: {g000,g001},{g010,g011},{g100,g101} via v_pk_fma_f32.
__device__ __forceinline__ void conv_voxel(const unsigned short* __restrict__ Bu,
                                           int rr, int x, const Kw& kw,
                                           float o[10]) {
    const unsigned short* row = Bu + rr * RSTRIDE + (x + 1);
    v2f gA = (v2f)(0.f), gB = (v2f)(0.f), gC = (v2f)(0.f);
    float g002 = 0, g020 = 0, g110 = 0, g200 = 0;
#pragma unroll
    for (int j = 0; j < KL; ++j) {
        float w0 = kw.k0[j], w1 = kw.k1[j], w2 = kw.k2[j];
        float b0 = bf_ld(row + 0 * CSTRIDE + j);
        float b1 = bf_ld(row + 1 * CSTRIDE + j);
        float b2 = bf_ld(row + 2 * CSTRIDE + j);
        float b3 = bf_ld(row + 3 * CSTRIDE + j);
        float b4 = bf_ld(row + 4 * CSTRIDE + j);
        float b5 = bf_ld(row + 5 * CSTRIDE + j);
        v2f w01 = {w0, w1};
        gA = pfma(w01, (v2f)(b0), gA);                     // {g000,g001}
        gB = pfma(w01, (v2f)(b1), gB);                     // {g010,g011}
        gC = pfma(w01, (v2f)(b3), gC);                     // {g100,g101}
        g002 = fmaf(w2, b0, g002);
        g020 = fmaf(w0, b2, g020);
        g110 = fmaf(w0, b4, g110);
        g200 = fmaf(w0, b5, g200);
    }
    float g000 = gA.x, g001 = gA.y, g010 = gB.x, g011 = gB.y;
    float g100 = gC.x, g101 = gC.y;
    float mass = g000;
    float denom = (mass > 0.f) ? mass : 1.f;
    float inv = 1.f / denom;
    float p = g100 * inv, q = g010 * inv, s = g001 * inv;
    const float cs = 1.0f / 25.0f;                         // 1/sigma^2
    o[0] = 0.5f - 0.1f * p;                                // 1/(2 sigma) = 0.1
    o[1] = 0.5f - 0.1f * q;
    o[2] = 0.5f - 0.1f * s;
    o[3] = (g200 * inv - p * p) * cs;
    o[4] = (g020 * inv - q * q) * cs;
    o[5] = (g002 * inv - s * s) * cs;
    o[6] = (g110 * inv - p * q) * cs;
    o[7] = (g011 * inv - q * s) * cs;
    o[8] = (g101 * inv - p * s) * cs;
    o[9] = mass;
#pragma unroll
    for (int c = 0; c < 10; ++c) o[c] = fminf(fmaxf(o[c], 0.f), 1.f);
}

__device__ __forceinline__ void do_voxel_out(const unsigned short* __restrict__ Bu,
                                             int rr, int x, int z0, int y0,
                                             float* __restrict__ out, const Kw& kw) {
    float o[10];
    conv_voxel(Bu, rr, x, kw, o);
    const int z2 = z0 + (rr >> 2), y2 = y0 + (rr & 3);
    const int v = (z2 * 128 + y2) * 128 + x;
#pragma unroll
    for (int c = 0; c < 10; ++c) out[(size_t)c * NV + v] = o[c];
}

__device__ __forceinline__ void zero_voxel(int rr, int x, int z0, int y0,
                                           float* __restrict__ out) {
    const int z2 = z0 + (rr >> 2), y2 = y0 + (rr & 3);
    const int v = (z2 * 128 + y2) * 128 + x;
#pragma unroll
    for (int c = 0; c < 10; ++c) out[(size_t)c * NV + v] = 0.f;
}

// -------- pass_yx: A[lab][3] bf16 -> out. 128 thr. -------------------------
// batched=1: grid (8192), lin = g + 8*lab + 64*l with l = (zsub<<5)|ytile:
//   - the 8 label-blocks of a tile share XCD and are adjacent -> out lines
//     union to 100% in L2 (write amp ~1; R22/R23-proven).
//   - ytile varies fastest -> 0.84 MB halo set << 4 MB XCD L2 -> A halo
//     loads are L2 hits, covered by the 2-deep pipeline (R23-proven).
// Body: R11 geometry + pk-FMA phase 1/2.
template <typename ST>
__global__ __launch_bounds__(128) void pass_yx(const unsigned short* __restrict__ A,
                                               const ST* __restrict__ seg,
                                               float* __restrict__ out,
                                               int label0, size_t a_stride,
                                               Kw kw, int batched) {
    __shared__ float kp[3][37];
    __shared__ __align__(16) unsigned short Bu[16 * RSTRIDE]; // 30,976 B
    __shared__ unsigned short lst[LCAP];                      // 1 KB
    __shared__ int cnt;

    // zero Bu (pads must be exactly 0) + weights + counter
    {
        uint4 z4 = make_uint4(0, 0, 0, 0);
        uint4* b4 = (uint4*)Bu;                            // 16*968/8 = 1936
        for (int i = threadIdx.x; i < 1936; i += 128) b4[i] = z4;
    }
    if (threadIdx.x < 37) {
        int i = threadIdx.x, j = i - 3; bool ok = (j >= 0) && (j < KL);
        kp[0][i] = ok ? kw.k0[j] : 0.f;
        kp[1][i] = ok ? kw.k1[j] : 0.f;
        kp[2][i] = ok ? kw.k2[j] : 0.f;
    }
    if (threadIdx.x == 0) cnt = 0;
    __syncthreads();

    // decode: XCD = b&7 always; batched path interleaves the 8 labels of a
    // tile at stride 8; within an XCD, ytile varies fastest (halo L2 reuse).
    const int b = blockIdx.x;
    const int g = b & 7;
    int labi, l;
    if (batched) { labi = (b >> 3) & 7; l = b >> 6; }      // 128 tiles/XCD
    else         { labi = 0;            l = b >> 3; }
    const int zsub = l >> 5, ytile = l & 31;               // ytile fastest
    const int label = label0 + labi;
    const unsigned short* Ab = A + (size_t)labi * a_stride;
    const int tx = threadIdx.x & 31, tz = threadIdx.x >> 5; // tz 0..3
    const int x0 = tx * 4;
    const int z0 = 16 * g + 4 * zsub;                      // XCD g owns z slab
    const int y0 = ytile * 4;                              // 32 y-tiles
    const int zs = (z0 + tz) * SLICE;

    // pre-issue compaction seg loads (complete under phase 1)
    const int rr_c = threadIdx.x >> 3, q0_c = threadIdx.x & 7;
    const int vrow_c = ((z0 + (rr_c >> 2)) * 128 + (y0 + (rr_c & 3))) * 128;
    unsigned pk[4];
#pragma unroll
    for (int k = 0; k < 4; ++k)
        pk[k] = seg_pack4(seg + vrow_c + 4 * (q0_c + 8 * k));

    // ---- phase 1: y-conv, T=4 outputs sliding in registers, 2-deep pipe ----
    v2f accL[6][4], accH[6][4];                            // [ch][t]
#pragma unroll
    for (int c = 0; c < 6; ++c)
#pragma unroll
        for (int t = 0; t < 4; ++t) { accL[c][t] = (v2f)(0.f); accH[c][t] = (v2f)(0.f); }

    uint2 c0 = make_uint2(0u, 0u), c1 = c0, c2 = c0;       // packed bf16 x4
    uint2 n0 = c0, n1 = c0, n2 = c0;
    {
        int yy = y0 - R;
        if ((unsigned)yy < 128u) {
            int base = zs + yy * 128 + x0;
            c0 = *(const uint2*)(Ab + base);
            c1 = *(const uint2*)(Ab + NV + base);
            c2 = *(const uint2*)(Ab + 2 * NV + base);
        }
        int yn = y0 + 1 - R;
        if ((unsigned)yn < 128u) {
            int base = zs + yn * 128 + x0;
            n0 = *(const uint2*)(Ab + base);
            n1 = *(const uint2*)(Ab + NV + base);
            n2 = *(const uint2*)(Ab + 2 * NV + base);
        }
    }
    for (int j = 0; j < 34; ++j) {
        uint2 f0 = make_uint2(0u, 0u), f1 = f0, f2 = f0;
        int yy = y0 + j + 2 - R;
        if (j < 32 && (unsigned)yy < 128u) {
            int base = zs + yy * 128 + x0;
            f0 = *(const uint2*)(Ab + base);
            f1 = *(const uint2*)(Ab + NV + base);
            f2 = *(const uint2*)(Ab + 2 * NV + base);
        }
        v2f a0l = bf2_v(c0.x), a0h = bf2_v(c0.y);
        v2f a1l = bf2_v(c1.x), a1h = bf2_v(c1.y);
        v2f a2l = bf2_v(c2.x), a2h = bf2_v(c2.y);
#pragma unroll
        for (int t = 0; t < 4; ++t) {
            int i = j - t + 3;
            v2f W0 = (v2f)(kp[0][i]);
            v2f W1 = (v2f)(kp[1][i]);
            v2f W2 = (v2f)(kp[2][i]);
            accL[0][t] = pfma(W0, a0l, accL[0][t]); accH[0][t] = pfma(W0, a0h, accH[0][t]);
            accL[1][t] = pfma(W1, a0l, accL[1][t]); accH[1][t] = pfma(W1, a0h, accH[1][t]);
            accL[2][t] = pfma(W2, a0l, accL[2][t]); accH[2][t] = pfma(W2, a0h, accH[2][t]);
            accL[3][t] = pfma(W0, a1l, accL[3][t]); accH[3][t] = pfma(W0, a1h, accH[3][t]);
            accL[4][t] = pfma(W1, a1l, accL[4][t]); accH[4][t] = pfma(W1, a1h, accH[4][t]);
            accL[5][t] = pfma(W0, a2l, accL[5][t]); accH[5][t] = pfma(W0, a2h, accH[5][t]);
        }
        c0 = n0; c1 = n1; c2 = n2;
        n0 = f0; n1 = f1; n2 = f2;
    }
#pragma unroll
    for (int t = 0; t < 4; ++t) {
        const int row = tz * 4 + t;                        // row = 4*zsub + ysub
#pragma unroll
        for (int c = 0; c < 6; ++c) {
            uint2 pv = make_uint2(pack_bf2(accL[c][t].x, accL[c][t].y),
                                  pack_bf2(accH[c][t].x, accH[c][t].y));
            *reinterpret_cast<uint2*>(Bu + row * RSTRIDE + c * CSTRIDE + 16 + x0) = pv;
        }
    }

    // ---- compaction: ballot-based, 1 atomic per wave per step ----
    {
        const int lane = threadIdx.x & 63;
        const unsigned long long below_mask = (1ull << lane) - 1ull;
#pragma unroll
        for (int k = 0; k < 4; ++k) {
            const unsigned w = pk[k];
#pragma unroll
            for (int t = 0; t < 4; ++t) {
                const int sv = (int)((w >> (8 * t)) & 255u);
                const int x = 4 * (q0_c + 8 * k) + t;
                const bool mt = (sv == label);
                const bool zt = !mt && (sv < 1 || sv > 8) &&
                                (((x & 7) + 1) == label);
                const bool pred = mt | zt;
                unsigned long long bal = __ballot(pred);
                int base = 0;
                if (lane == 0 && bal) base = atomicAdd(&cnt, (int)__popcll(bal));
                base = __shfl(base, 0);
                if (pred) {
                    int pos = base + (int)__popcll(bal & below_mask);
                    if (pos < LCAP)
                        lst[pos] = (unsigned short)((rr_c << 7) | x | (zt ? 0x8000 : 0));
                }
            }
        }
    }

    __syncthreads();

    // ---- phase 2: sparse x-conv + epilogue (or zero-store) ----
    const int total = cnt;
    if (total <= LCAP) {
        for (int e = threadIdx.x; e < total; e += 128) {
            int ent = lst[e];
            int rr = (ent >> 7) & 15, x = ent & 127;
            if (ent & 0x8000) zero_voxel(rr, x, z0, y0, out);
            else do_voxel_out(Bu, rr, x, z0, y0, out, kw);
        }
    } else {
        // adversarial-density fallback: dense masked sweep (same math)
        for (int e = threadIdx.x; e < 2048; e += 128) {
            int rr = e >> 7, x = e & 127;
            int z2 = z0 + (rr >> 2), y2 = y0 + (rr & 3);
            int sv = (int)seg[(z2 * 128 + y2) * 128 + x] & 255;
            if (sv == label)
                do_voxel_out(Bu, rr, x, z0, y0, out, kw);
            else if ((sv < 1 || sv > 8) && (((x & 7) + 1) == label))
                zero_voxel(rr, x, z0, y0, out);
        }
    }
}

__global__ __launch_bounds__(256) void seg_to_u8(const int* __restrict__ seg,
                                                 unsigned char* __restrict__ seg8) {
    const int t = blockIdx.x * 256 + threadIdx.x;          // 2048 blocks
    const int4 s = ((const int4*)seg)[t];
    ((uchar4*)seg8)[t] = make_uchar4((unsigned char)s.x, (unsigned char)s.y,
                                     (unsigned char)s.z, (unsigned char)s.w);
}

extern "C" void kernel_launch(void* const* d_in, const int* in_sizes, int n_in,
                              void* d_out, int out_size, void* d_ws, size_t ws_size,
                              hipStream_t stream) {
    const int* seg = (const int*)d_in[0];
    // d_in[1] (coords) unused: math is translation-invariant.
    float* out = (float*)d_out;
    unsigned short* A = (unsigned short*)d_ws;             // bf16 A planes
    const size_t AVOL = (size_t)3 * NV;                    // u16 elements/label

    Kw kw;
    double gg[KL], S = 0.0;
    for (int j = 0; j < KL; ++j) { double d = j - R; gg[j] = exp(-0.5 * d * d / 25.0); S += gg[j]; }
    for (int j = 0; j < KL; ++j) {
        double gn = gg[j] / S, d = j - R;
        kw.k0[j] = (float)gn;
        kw.k1[j] = (float)(-d * gn);   // conv kernel k1 evaluated at (Z - t) = -d
        kw.k2[j] = (float)(d * d * gn);
    }

    // No memset: every output voxel is written exactly once across labels.

    const size_t need_all = 8 * AVOL * sizeof(unsigned short) + NV;  // A_all + seg8
    const size_t need_one = AVOL * sizeof(unsigned short) + NV;

    if (ws_size >= need_all) {
        // 3-dispatch path: label-adjacent linearization in pass_yx.
        unsigned char* seg8 = (unsigned char*)d_ws + 8 * AVOL * sizeof(unsigned short);
        seg_to_u8<<<dim3(2048), dim3(256), 0, stream>>>(seg, seg8);
        pass_z_t<unsigned char><<<dim3(512, 8), dim3(256), 0, stream>>>(
            seg8, A, 1, AVOL, kw);
        pass_yx<unsigned char><<<dim3(8192, 1), dim3(128), 0, stream>>>(
            A, seg8, out, 1, AVOL, kw, 1);
    } else if (ws_size >= need_one) {
        unsigned char* seg8 = (unsigned char*)d_ws + AVOL * sizeof(unsigned short);
        seg_to_u8<<<dim3(2048), dim3(256), 0, stream>>>(seg, seg8);
        for (int label = 1; label <= 8; ++label) {
            pass_z_t<unsigned char><<<dim3(512, 1), dim3(256), 0, stream>>>(
                seg8, A, label, 0, kw);
            pass_yx<unsigned char><<<dim3(1024, 1), dim3(128), 0, stream>>>(
                A, seg8, out, label, 0, kw, 0);
        }
    } else {
        for (int label = 1; label <= 8; ++label) {
            pass_z_t<int><<<dim3(512, 1), dim3(256), 0, stream>>>(
                seg, A, label, 0, kw);
            pass_yx<int><<<dim3(1024, 1), dim3(128), 0, stream>>>(
                A, seg, out, label, 0, kw, 0);
        }
    }
}

// Round 17
// 366.634 us; speedup vs baseline: 1.1673x; 1.0175x over previous
//
#include <hip/hip_runtime.h>
#include <hip/hip_bf16.h>
#include <math.h>

// LSD (local shape descriptors), 128^3, 8 labels, sigma=5, truncate=3 -> 31-tap kernel.
//
// Algebra: for label mask m, define G_{abc} = (k_a *_z)(k_b *_y)(k_c *_x) m with
//   k0(u)=w(u), k1(u)=u w(u), k2(u)=u^2 w(u)  (w = normalized gaussian).
// At a voxel with mass=G000>0, p=G100/mass, q=G010/mass, s=G001/mass:
//   mean_offset = 0.5 - {p,q,s}/(2 sigma);  cov_ab = (G../mass - ..)/sigma^2.
// Translation-invariant: coords input not needed. Masks disjoint.
//
// Measured record (totals; pass_yx in parens):
//   R11 407 (289)  R22 401 (279)  R23 385 (265)  R24 373 (255, BEST):
//   write-merge (WRITE 448->90, amp~1) + y-halo L2 (FETCH 206->50) +
//   pk-FMA phase 1 (conflicts also 1.9M->818K via v2f epilogue).
//   Traffic compulsory; VALUBusy 52.8%; occ 21% (TLP refuted).
// R25 (this round): finish the pk conversion -- phase 2 tap-pair packing.
//   conv_voxel: 10 v2f accumulators over (j,j+1) tap pairs; weights
//   {k[j],k[j+1]} are compile-time v2f in the unrolled loop; b-pairs reuse
//   the SAME u16 loads as before (memory pattern byte-identical, proven).
//   20 scalar FMA/pair -> 10 pk; 15 pairs + scalar tap 30 + 10 horizontal
//   adds. ~330 instr/thread saved (~9% of pass_yx issue).
//   Everything else R24-byte-identical.

constexpr int NV = 128 * 128 * 128;
constexpr int SLICE = 128 * 128;
constexpr int R = 15;
constexpr int KL = 31;
constexpr int CSTRIDE = 160;            // u16: 16 pad + 128 data + 16 pad
constexpr int RSTRIDE = 6 * CSTRIDE + 8; // 968 u16; row stagger: 242w = 18 mod 32
constexpr int LCAP = 512;

struct Kw { float k0[KL]; float k1[KL]; float k2[KL]; };

typedef float v2f __attribute__((ext_vector_type(2)));

__device__ __forceinline__ v2f pfma(v2f w, v2f b, v2f acc) {
    return __builtin_elementwise_fma(w, b, acc);
}

__device__ __forceinline__ float4 load_mask4(const unsigned char* p, int lab) {
    unsigned int u = *(const unsigned int*)p;
    return make_float4(((u       ) & 255u) == (unsigned)lab ? 1.f : 0.f,
                       ((u >>  8 ) & 255u) == (unsigned)lab ? 1.f : 0.f,
                       ((u >> 16 ) & 255u) == (unsigned)lab ? 1.f : 0.f,
                       ((u >> 24 ) & 255u) == (unsigned)lab ? 1.f : 0.f);
}
__device__ __forceinline__ float4 load_mask4(const int* p, int lab) {
    int4 s = *(const int4*)p;
    return make_float4(s.x == lab ? 1.f : 0.f, s.y == lab ? 1.f : 0.f,
                       s.z == lab ? 1.f : 0.f, s.w == lab ? 1.f : 0.f);
}

__device__ __forceinline__ unsigned seg_pack4(const unsigned char* p) {
    return *(const unsigned int*)p;
}
__device__ __forceinline__ unsigned seg_pack4(const int* p) {
    int4 v = *(const int4*)p;
    return (unsigned)(v.x & 255) | ((unsigned)(v.y & 255) << 8) |
           ((unsigned)(v.z & 255) << 16) | ((unsigned)(v.w & 255) << 24);
}

__device__ __forceinline__ float bf_ld(const unsigned short* p) {
    return __uint_as_float(((unsigned int)(*p)) << 16);
}

// packed bf16 pair (u32) -> v2f {lo, hi}. 1 VALU op per value.
__device__ __forceinline__ v2f bf2_v(unsigned u) {
    v2f r;
    r.x = __uint_as_float(u << 16);
    r.y = __uint_as_float(u & 0xFFFF0000u);
    return r;
}

__device__ __forceinline__ unsigned pack_bf2(float a, float b) {
    __hip_bfloat162 h = __float22bfloat162_rn(make_float2(a, b));
    return *reinterpret_cast<unsigned*>(&h);
}

// -------- pass_z: seg -> A[lab][3] bf16 (z-conv). grid (512, nlab), 256 thr.
// Proven form: 4-x threads, 2-deep pipelined window, kp table, pk-FMA.
template <typename ST>
__global__ __launch_bounds__(256) void pass_z_t(const ST* __restrict__ seg,
                                                unsigned short* __restrict__ A,
                                                int label0, size_t a_stride,
                                                Kw kw) {
    __shared__ float kp[3][37];           // zero-padded: kp[c][i] = k_c[i-3]
    if (threadIdx.x < 37) {
        int i = threadIdx.x, j = i - 3; bool ok = (j >= 0) && (j < KL);
        kp[0][i] = ok ? kw.k0[j] : 0.f;
        kp[1][i] = ok ? kw.k1[j] : 0.f;
        kp[2][i] = ok ? kw.k2[j] : 0.f;
    }
    __syncthreads();
    const int label = label0 + blockIdx.y;
    unsigned short* Ab = A + (size_t)blockIdx.y * a_stride;
    const int h = blockIdx.x, g = h & 7, l = h >> 3;       // 512 x-blocks
    const int tx = threadIdx.x & 31, ty = threadIdx.x >> 5;
    const int x0 = tx * 4;
    const int z0 = 16 * g + 4 * (l & 3);                   // XCD g owns z [16g,16g+16)
    const int y  = (l >> 2) * 8 + ty;

    v2f accL[4][3], accH[4][3];
#pragma unroll
    for (int t = 0; t < 4; ++t)
#pragma unroll
        for (int c = 0; c < 3; ++c) { accL[t][c] = (v2f)(0.f); accH[t][c] = (v2f)(0.f); }

    // 2-deep pipelined sliding window: load j+2 while FMAing j.
    float4 cm = make_float4(0.f, 0.f, 0.f, 0.f), nm = cm;
    {
        int zz = z0 - R;
        if ((unsigned)zz < 128u)
            cm = load_mask4(seg + (zz * SLICE + y * 128 + x0), label);
        int zn = z0 + 1 - R;
        if ((unsigned)zn < 128u)
            nm = load_mask4(seg + (zn * SLICE + y * 128 + x0), label);
    }
    for (int j = 0; j < 34; ++j) {                         // window: 4 outs + 30
        float4 fm = make_float4(0.f, 0.f, 0.f, 0.f);
        int zz = z0 + j + 2 - R;                           // uniform per wave
        if (j < 32 && (unsigned)zz < 128u)
            fm = load_mask4(seg + (zz * SLICE + y * 128 + x0), label);
        v2f cl = {cm.x, cm.y}, ch = {cm.z, cm.w};
#pragma unroll
        for (int t = 0; t < 4; ++t) {
            int i = j - t + 3;                             // padded weight index
            v2f W0 = (v2f)(kp[0][i]);
            v2f W1 = (v2f)(kp[1][i]);
            v2f W2 = (v2f)(kp[2][i]);
            accL[t][0] = pfma(W0, cl, accL[t][0]); accH[t][0] = pfma(W0, ch, accH[t][0]);
            accL[t][1] = pfma(W1, cl, accL[t][1]); accH[t][1] = pfma(W1, ch, accH[t][1]);
            accL[t][2] = pfma(W2, cl, accL[t][2]); accH[t][2] = pfma(W2, ch, accH[t][2]);
        }
        cm = nm; nm = fm;
    }
#pragma unroll
    for (int t = 0; t < 4; ++t) {
        int base = (z0 + t) * SLICE + y * 128 + x0;
#pragma unroll
        for (int c = 0; c < 3; ++c) {
            uint2 pv = make_uint2(pack_bf2(accL[t][c].x, accL[t][c].y),
                                  pack_bf2(accH[t][c].x, accH[t][c].y));
            *reinterpret_cast<uint2*>(Ab + (size_t)c * NV + base) = pv;
        }
    }
}

// ---- per-voxel sparse x-conv + epilogue (B rows in bf16 LDS, zero-padded) -
// Tap-pair packed: 10 v2f accumulators over (j,j+1); weights are
// compile-time v2f pairs; b-pairs reuse the same u16 loads as before.
__device__ __forceinline__ void conv_voxel(const unsigned short* __restrict__ Bu,
                                           int rr, int x, const Kw& kw,
                                           float o[10]) {
    const unsigned short* row = Bu + rr * RSTRIDE + (x + 1);
    v2f a000 = (v2f)(0.f), a001 = a000, a002 = a000, a010 = a000, a011 = a000,
        a020 = a000, a100 = a000, a101 = a000, a110 = a000, a200 = a000;
#pragma unroll
    for (int jp = 0; jp < 15; ++jp) {
        const int j = 2 * jp;
        v2f w0 = {kw.k0[j], kw.k0[j + 1]};
        v2f w1 = {kw.k1[j], kw.k1[j + 1]};
        v2f w2 = {kw.k2[j], kw.k2[j + 1]};
        v2f b0 = {bf_ld(row + 0 * CSTRIDE + j), bf_ld(row + 0 * CSTRIDE + j + 1)};
        v2f b1 = {bf_ld(row + 1 * CSTRIDE + j), bf_ld(row + 1 * CSTRIDE + j + 1)};
        v2f b2 = {bf_ld(row + 2 * CSTRIDE + j), bf_ld(row + 2 * CSTRIDE + j + 1)};
        v2f b3 = {bf_ld(row + 3 * CSTRIDE + j), bf_ld(row + 3 * CSTRIDE + j + 1)};
        v2f b4 = {bf_ld(row + 4 * CSTRIDE + j), bf_ld(row + 4 * CSTRIDE + j + 1)};
        v2f b5 = {bf_ld(row + 5 * CSTRIDE + j), bf_ld(row + 5 * CSTRIDE + j + 1)};
        a000 = pfma(w0, b0, a000); a001 = pfma(w1, b0, a001); a002 = pfma(w2, b0, a002);
        a010 = pfma(w0, b1, a010); a011 = pfma(w1, b1, a011);
        a020 = pfma(w0, b2, a020);
        a100 = pfma(w0, b3, a100); a101 = pfma(w1, b3, a101);
        a110 = pfma(w0, b4, a110);
        a200 = pfma(w0, b5, a200);
    }
    // remainder tap j = 30 (KL = 31) + horizontal reduce
    {
        const int j = 30;
        float w0 = kw.k0[j], w1 = kw.k1[j], w2 = kw.k2[j];
        float b0 = bf_ld(row + 0 * CSTRIDE + j);
        float b1 = bf_ld(row + 1 * CSTRIDE + j);
        float b2 = bf_ld(row + 2 * CSTRIDE + j);
        float b3 = bf_ld(row + 3 * CSTRIDE + j);
        float b4 = bf_ld(row + 4 * CSTRIDE + j);
        float b5 = bf_ld(row + 5 * CSTRIDE + j);
        float g000 = fmaf(w0, b0, a000.x + a000.y);
        float g001 = fmaf(w1, b0, a001.x + a001.y);
        float g002 = fmaf(w2, b0, a002.x + a002.y);
        float g010 = fmaf(w0, b1, a010.x + a010.y);
        float g011 = fmaf(w1, b1, a011.x + a011.y);
        float g020 = fmaf(w0, b2, a020.x + a020.y);
        float g100 = fmaf(w0, b3, a100.x + a100.y);
        float g101 = fmaf(w1, b3, a101.x + a101.y);
        float g110 = fmaf(w0, b4, a110.x + a110.y);
        float g200 = fmaf(w0, b5, a200.x + a200.y);

        float mass = g000;
        float denom = (mass > 0.f) ? mass : 1.f;
        float inv = 1.f / denom;
        float p = g100 * inv, q = g010 * inv, s = g001 * inv;
        const float cs = 1.0f / 25.0f;                     // 1/sigma^2
        o[0] = 0.5f - 0.1f * p;                            // 1/(2 sigma) = 0.1
        o[1] = 0.5f - 0.1f * q;
        o[2] = 0.5f - 0.1f * s;
        o[3] = (g200 * inv - p * p) * cs;
        o[4] = (g020 * inv - q * q) * cs;
        o[5] = (g002 * inv - s * s) * cs;
        o[6] = (g110 * inv - p * q) * cs;
        o[7] = (g011 * inv - q * s) * cs;
        o[8] = (g101 * inv - p * s) * cs;
        o[9] = mass;
    }
#pragma unroll
    for (int c = 0; c < 10; ++c) o[c] = fminf(fmaxf(o[c], 0.f), 1.f);
}

__device__ __forceinline__ void do_voxel_out(const unsigned short* __restrict__ Bu,
                                             int rr, int x, int z0, int y0,
                                             float* __restrict__ out, const Kw& kw) {
    float o[10];
    conv_voxel(Bu, rr, x, kw, o);
    const int z2 = z0 + (rr >> 2), y2 = y0 + (rr & 3);
    const int v = (z2 * 128 + y2) * 128 + x;
#pragma unroll
    for (int c = 0; c < 10; ++c) out[(size_t)c * NV + v] = o[c];
}

__device__ __forceinline__ void zero_voxel(int rr, int x, int z0, int y0,
                                           float* __restrict__ out) {
    const int z2 = z0 + (rr >> 2), y2 = y0 + (rr & 3);
    const int v = (z2 * 128 + y2) * 128 + x;
#pragma unroll
    for (int c = 0; c < 10; ++c) out[(size_t)c * NV + v] = 0.f;
}

// -------- pass_yx: A[lab][3] bf16 -> out. 128 thr. -------------------------
// batched=1: grid (8192), lin = g + 8*lab + 64*l with l = (zsub<<5)|ytile:
//   - the 8 label-blocks of a tile share XCD and are adjacent -> out lines
//     union to 100% in L2 (write amp ~1; R22/R23-proven).
//   - ytile varies fastest -> 0.84 MB halo set << 4 MB XCD L2 -> A halo
//     loads are L2 hits, covered by the 2-deep pipeline (R23-proven).
// Body: R11 geometry + pk-FMA phase 1 (R24) + tap-pair pk phase 2 (R25).
template <typename ST>
__global__ __launch_bounds__(128) void pass_yx(const unsigned short* __restrict__ A,
                                               const ST* __restrict__ seg,
                                               float* __restrict__ out,
                                               int label0, size_t a_stride,
                                               Kw kw, int batched) {
    __shared__ float kp[3][37];
    __shared__ __align__(16) unsigned short Bu[16 * RSTRIDE]; // 30,976 B
    __shared__ unsigned short lst[LCAP];                      // 1 KB
    __shared__ int cnt;

    // zero Bu (pads must be exactly 0) + weights + counter
    {
        uint4 z4 = make_uint4(0, 0, 0, 0);
        uint4* b4 = (uint4*)Bu;                            // 16*968/8 = 1936
        for (int i = threadIdx.x; i < 1936; i += 128) b4[i] = z4;
    }
    if (threadIdx.x < 37) {
        int i = threadIdx.x, j = i - 3; bool ok = (j >= 0) && (j < KL);
        kp[0][i] = ok ? kw.k0[j] : 0.f;
        kp[1][i] = ok ? kw.k1[j] : 0.f;
        kp[2][i] = ok ? kw.k2[j] : 0.f;
    }
    if (threadIdx.x == 0) cnt = 0;
    __syncthreads();

    // decode: XCD = b&7 always; batched path interleaves the 8 labels of a
    // tile at stride 8; within an XCD, ytile varies fastest (halo L2 reuse).
    const int b = blockIdx.x;
    const int g = b & 7;
    int labi, l;
    if (batched) { labi = (b >> 3) & 7; l = b >> 6; }      // 128 tiles/XCD
    else         { labi = 0;            l = b >> 3; }
    const int zsub = l >> 5, ytile = l & 31;               // ytile fastest
    const int label = label0 + labi;
    const unsigned short* Ab = A + (size_t)labi * a_stride;
    const int tx = threadIdx.x & 31, tz = threadIdx.x >> 5; // tz 0..3
    const int x0 = tx * 4;
    const int z0 = 16 * g + 4 * zsub;                      // XCD g owns z slab
    const int y0 = ytile * 4;                              // 32 y-tiles
    const int zs = (z0 + tz) * SLICE;

    // pre-issue compaction seg loads (complete under phase 1)
    const int rr_c = threadIdx.x >> 3, q0_c = threadIdx.x & 7;
    const int vrow_c = ((z0 + (rr_c >> 2)) * 128 + (y0 + (rr_c & 3))) * 128;
    unsigned pk[4];
#pragma unroll
    for (int k = 0; k < 4; ++k)
        pk[k] = seg_pack4(seg + vrow_c + 4 * (q0_c + 8 * k));

    // ---- phase 1: y-conv, T=4 outputs sliding in registers, 2-deep pipe ----
    v2f accL[6][4], accH[6][4];                            // [ch][t]
#pragma unroll
    for (int c = 0; c < 6; ++c)
#pragma unroll
        for (int t = 0; t < 4; ++t) { accL[c][t] = (v2f)(0.f); accH[c][t] = (v2f)(0.f); }

    uint2 c0 = make_uint2(0u, 0u), c1 = c0, c2 = c0;       // packed bf16 x4
    uint2 n0 = c0, n1 = c0, n2 = c0;
    {
        int yy = y0 - R;
        if ((unsigned)yy < 128u) {
            int base = zs + yy * 128 + x0;
            c0 = *(const uint2*)(Ab + base);
            c1 = *(const uint2*)(Ab + NV + base);
            c2 = *(const uint2*)(Ab + 2 * NV + base);
        }
        int yn = y0 + 1 - R;
        if ((unsigned)yn < 128u) {
            int base = zs + yn * 128 + x0;
            n0 = *(const uint2*)(Ab + base);
            n1 = *(const uint2*)(Ab + NV + base);
            n2 = *(const uint2*)(Ab + 2 * NV + base);
        }
    }
    for (int j = 0; j < 34; ++j) {
        uint2 f0 = make_uint2(0u, 0u), f1 = f0, f2 = f0;
        int yy = y0 + j + 2 - R;
        if (j < 32 && (unsigned)yy < 128u) {
            int base = zs + yy * 128 + x0;
            f0 = *(const uint2*)(Ab + base);
            f1 = *(const uint2*)(Ab + NV + base);
            f2 = *(const uint2*)(Ab + 2 * NV + base);
        }
        v2f a0l = bf2_v(c0.x), a0h = bf2_v(c0.y);
        v2f a1l = bf2_v(c1.x), a1h = bf2_v(c1.y);
        v2f a2l = bf2_v(c2.x), a2h = bf2_v(c2.y);
#pragma unroll
        for (int t = 0; t < 4; ++t) {
            int i = j - t + 3;
            v2f W0 = (v2f)(kp[0][i]);
            v2f W1 = (v2f)(kp[1][i]);
            v2f W2 = (v2f)(kp[2][i]);
            accL[0][t] = pfma(W0, a0l, accL[0][t]); accH[0][t] = pfma(W0, a0h, accH[0][t]);
            accL[1][t] = pfma(W1, a0l, accL[1][t]); accH[1][t] = pfma(W1, a0h, accH[1][t]);
            accL[2][t] = pfma(W2, a0l, accL[2][t]); accH[2][t] = pfma(W2, a0h, accH[2][t]);
            accL[3][t] = pfma(W0, a1l, accL[3][t]); accH[3][t] = pfma(W0, a1h, accH[3][t]);
            accL[4][t] = pfma(W1, a1l, accL[4][t]); accH[4][t] = pfma(W1, a1h, accH[4][t]);
            accL[5][t] = pfma(W0, a2l, accL[5][t]); accH[5][t] = pfma(W0, a2h, accH[5][t]);
        }
        c0 = n0; c1 = n1; c2 = n2;
        n0 = f0; n1 = f1; n2 = f2;
    }
#pragma unroll
    for (int t = 0; t < 4; ++t) {
        const int row = tz * 4 + t;                        // row = 4*zsub + ysub
#pragma unroll
        for (int c = 0; c < 6; ++c) {
            uint2 pv = make_uint2(pack_bf2(accL[c][t].x, accL[c][t].y),
                                  pack_bf2(accH[c][t].x, accH[c][t].y));
            *reinterpret_cast<uint2*>(Bu + row * RSTRIDE + c * CSTRIDE + 16 + x0) = pv;
        }
    }

    // ---- compaction: ballot-based, 1 atomic per wave per step ----
    {
        const int lane = threadIdx.x & 63;
        const unsigned long long below_mask = (1ull << lane) - 1ull;
#pragma unroll
        for (int k = 0; k < 4; ++k) {
            const unsigned w = pk[k];
#pragma unroll
            for (int t = 0; t < 4; ++t) {
                const int sv = (int)((w >> (8 * t)) & 255u);
                const int x = 4 * (q0_c + 8 * k) + t;
                const bool mt = (sv == label);
                const bool zt = !mt && (sv < 1 || sv > 8) &&
                                (((x & 7) + 1) == label);
                const bool pred = mt | zt;
                unsigned long long bal = __ballot(pred);
                int base = 0;
                if (lane == 0 && bal) base = atomicAdd(&cnt, (int)__popcll(bal));
                base = __shfl(base, 0);
                if (pred) {
                    int pos = base + (int)__popcll(bal & below_mask);
                    if (pos < LCAP)
                        lst[pos] = (unsigned short)((rr_c << 7) | x | (zt ? 0x8000 : 0));
                }
            }
        }
    }

    __syncthreads();

    // ---- phase 2: sparse x-conv + epilogue (or zero-store) ----
    const int total = cnt;
    if (total <= LCAP) {
        for (int e = threadIdx.x; e < total; e += 128) {
            int ent = lst[e];
            int rr = (ent >> 7) & 15, x = ent & 127;
            if (ent & 0x8000) zero_voxel(rr, x, z0, y0, out);
            else do_voxel_out(Bu, rr, x, z0, y0, out, kw);
        }
    } else {
        // adversarial-density fallback: dense masked sweep (same math)
        for (int e = threadIdx.x; e < 2048; e += 128) {
            int rr = e >> 7, x = e & 127;
            int z2 = z0 + (rr >> 2), y2 = y0 + (rr & 3);
            int sv = (int)seg[(z2 * 128 + y2) * 128 + x] & 255;
            if (sv == label)
                do_voxel_out(Bu, rr, x, z0, y0, out, kw);
            else if ((sv < 1 || sv > 8) && (((x & 7) + 1) == label))
                zero_voxel(rr, x, z0, y0, out);
        }
    }
}

__global__ __launch_bounds__(256) void seg_to_u8(const int* __restrict__ seg,
                                                 unsigned char* __restrict__ seg8) {
    const int t = blockIdx.x * 256 + threadIdx.x;          // 2048 blocks
    const int4 s = ((const int4*)seg)[t];
    ((uchar4*)seg8)[t] = make_uchar4((unsigned char)s.x, (unsigned char)s.y,
                                     (unsigned char)s.z, (unsigned char)s.w);
}

extern "C" void kernel_launch(void* const* d_in, const int* in_sizes, int n_in,
                              void* d_out, int out_size, void* d_ws, size_t ws_size,
                              hipStream_t stream) {
    const int* seg = (const int*)d_in[0];
    // d_in[1] (coords) unused: math is translation-invariant.
    float* out = (float*)d_out;
    unsigned short* A = (unsigned short*)d_ws;             // bf16 A planes
    const size_t AVOL = (size_t)3 * NV;                    // u16 elements/label

    Kw kw;
    double gg[KL], S = 0.0;
    for (int j = 0; j < KL; ++j) { double d = j - R; gg[j] = exp(-0.5 * d * d / 25.0); S += gg[j]; }
    for (int j = 0; j < KL; ++j) {
        double gn = gg[j] / S, d = j - R;
        kw.k0[j] = (float)gn;
        kw.k1[j] = (float)(-d * gn);   // conv kernel k1 evaluated at (Z - t) = -d
        kw.k2[j] = (float)(d * d * gn);
    }

    // No memset: every output voxel is written exactly once across labels.

    const size_t need_all = 8 * AVOL * sizeof(unsigned short) + NV;  // A_all + seg8
    const size_t need_one = AVOL * sizeof(unsigned short) + NV;

    if (ws_size >= need_all) {
        // 3-dispatch path: label-adjacent linearization in pass_yx.
        unsigned char* seg8 = (unsigned char*)d_ws + 8 * AVOL * sizeof(unsigned short);
        seg_to_u8<<<dim3(2048), dim3(256), 0, stream>>>(seg, seg8);
        pass_z_t<unsigned char><<<dim3(512, 8), dim3(256), 0, stream>>>(
            seg8, A, 1, AVOL, kw);
        pass_yx<unsigned char><<<dim3(8192, 1), dim3(128), 0, stream>>>(
            A, seg8, out, 1, AVOL, kw, 1);
    } else if (ws_size >= need_one) {
        unsigned char* seg8 = (unsigned char*)d_ws + AVOL * sizeof(unsigned short);
        seg_to_u8<<<dim3(2048), dim3(256), 0, stream>>>(seg, seg8);
        for (int label = 1; label <= 8; ++label) {
            pass_z_t<unsigned char><<<dim3(512, 1), dim3(256), 0, stream>>>(
                seg8, A, label, 0, kw);
            pass_yx<unsigned char><<<dim3(1024, 1), dim3(128), 0, stream>>>(
                A, seg8, out, label, 0, kw, 0);
        }
    } else {
        for (int label = 1; label <= 8; ++label) {
            pass_z_t<int><<<dim3(512, 1), dim3(256), 0, stream>>>(
                seg, A, label, 0, kw);
            pass_yx<int><<<dim3(1024, 1), dim3(128), 0, stream>>>(
                A, seg, out, label, 0, kw, 0);
        }
    }
}